// Round 5
// baseline (732.352 us; speedup 1.0000x reference)
//
#include <hip/hip_runtime.h>
#include <math.h>

// ---------------------------------------------------------------------------
// LiDARPriorQueryGenerator — MI355X (gfx950). FP32 I/O per reference dtypes.
// prep(w-reorder bf16 + fp32 transpose, bn-fold) -> NHWC bf16 (W padded 130)
// -> conv1 MFMA -> featb bf16 -> conv2 MFMA + fused 1x1 score (atomicAdd
// logits) -> RADIX-SELECT top>=128 -> EXACT fp32 rescore (G=2 candidates per
// block, coalesced [tap][ci][co] weights) -> final top-100 -> fused
// FFN/LN/heads/anchor.
// ---------------------------------------------------------------------------

typedef __attribute__((ext_vector_type(8))) short bf16x8;
typedef __attribute__((ext_vector_type(4))) float f32x4;

#define HW 16384
#define WPITCH 130   // padded width: col 0 and 129 are zero pads
#define CCAP 192     // candidate cap (count(key>=K*) typically 128..~132)
// workspace byte offsets
#define WSO_XN    0ULL           // bf16 NHWC padded input  (34,078,720)
#define WSO_FEATB 34078720ULL    // bf16 NHWC padded feat   (34,078,720)
#define WSO_WP1   68157440ULL    // bf16 [9][256][256] shared_w
#define WSO_WP2   69337088ULL    // bf16 [9][256][256] obj_w1
#define WSO_BNP   70516736ULL    // fp32 scale1,shift1,scale2,shift2,w2f (1280)
#define WSO_LOG   70521856ULL    // fp32 65536 logits
#define WSO_CAND  70784000ULL    // int 4*CCAP
#define WSO_CNT   70787072ULL    // int 4 (+pad)
#define WSO_EXL   70787136ULL    // fp32 4*CCAP
#define WSO_TIDX  70790208ULL    // int 4*100
#define WSO_TLOG  70791808ULL    // fp32 4*100
#define WSO_W1T   70793408ULL    // fp32 [tap][ci][co] shared_w (2,359,296)
#define WSO_W2T   73152704ULL    // fp32 [tap][ci][co] obj_w1   (2,359,296)

__device__ __forceinline__ float bf2f(short s) {
  return __uint_as_float(((unsigned)(unsigned short)s) << 16);
}
__device__ __forceinline__ short f2bf(float f) {  // RNE
  unsigned u = __float_as_uint(f);
  u += 0x7fffu + ((u >> 16) & 1u);
  return (short)(u >> 16);
}
__device__ __forceinline__ void gll16(const void* g, void* l) {
  __builtin_amdgcn_global_load_lds(
      (const __attribute__((address_space(1))) void*)g,
      (__attribute__((address_space(3))) void*)l, 16, 0, 0);
}

// --- prep: reorder conv weights (co,ci,kh,kw) f32 -> [tap][co][ci] bf16 -----
__global__ void wreorder(const float* __restrict__ src, short* __restrict__ dst) {
  int i = blockIdx.x * 256 + threadIdx.x;  // grid 2304
  int ci = i & 255;
  int r = i >> 8;
  int co = r & 255;
  int tap = r >> 8;
  dst[i] = f2bf(src[(co * 256 + ci) * 9 + tap]);
}

// --- prep: transpose conv weights f32 -> [tap][ci][co] fp32 (for rescore) ---
__global__ void wtrans(const float* __restrict__ src, float* __restrict__ dst) {
  int i = blockIdx.x * 256 + threadIdx.x;  // grid 2304
  int co = i & 255;
  int r = i >> 8;
  int ci = r & 255;
  int tap = r >> 8;
  dst[i] = src[(co * 256 + ci) * 9 + tap];
}

// --- prep: fold BN into scale/shift (fp32-exact), copy w2 -------------------
__global__ void bnprep(const float* g1, const float* b1, const float* m1,
                       const float* v1, const float* g2, const float* b2,
                       const float* m2, const float* v2, const float* w2,
                       float* __restrict__ out) {
  int c = threadIdx.x;
  float s1 = g1[c] / sqrtf(v1[c] + 1e-5f);
  out[c] = s1;
  out[256 + c] = b1[c] - m1[c] * s1;
  float s2 = g2[c] / sqrtf(v2[c] + 1e-5f);
  out[512 + c] = s2;
  out[768 + c] = b2[c] - m2[c] * s2;
  out[1024 + c] = w2[c];
}

// --- zero the W-pad columns of xn and featb ---------------------------------
__global__ void padzero(short* __restrict__ xn, short* __restrict__ featb) {
  int i = blockIdx.x * 256 + threadIdx.x;  // grid 1024 -> 262144
  int c = i & 255;
  int r = i >> 8;            // 0..1023 : nh(512) x side(2)
  int nh = r >> 1;
  int side = r & 1;
  size_t off = ((size_t)nh * WPITCH + (side ? 129 : 0)) * 256 + c;
  xn[off] = 0;
  featb[off] = 0;
}

// --- logits init to 1x1 bias ------------------------------------------------
__global__ void loginit(float* __restrict__ logits, const float* __restrict__ b2) {
  logits[blockIdx.x * 256 + threadIdx.x] = b2[0];
}

// --- NCHW f32 -> NHWC bf16 (padded W) ---------------------------------------
__global__ __launch_bounds__(256) void nchw2nhwc(const float* __restrict__ in,
                                                 short* __restrict__ out) {
  __shared__ short tl[64 * 66];
  int n = blockIdx.z, c0 = blockIdx.y * 64, s0 = blockIdx.x * 64;
  int sl = threadIdx.x & 63, cl = threadIdx.x >> 6;
  for (int p = 0; p < 16; ++p) {
    int c = cl + p * 4;
    tl[c * 66 + sl] = f2bf(in[(((size_t)(n * 256 + c0 + c)) << 14) + s0 + sl]);
  }
  __syncthreads();
  int co = threadIdx.x & 63, so = threadIdx.x >> 6;
  for (int p = 0; p < 16; ++p) {
    int S = s0 + so + p * 4;
    int h = S >> 7, w = S & 127;
    out[(((size_t)(n * 128 + h)) * WPITCH + w + 1) * 256 + c0 + co] =
        tl[co * 66 + (so + p * 4)];
  }
}

// --- 3x3 conv + BN + ReLU via MFMA; OUT_LOGITS fuses the 1x1 score ----------
template <int OUT_LOGITS>
__global__ __launch_bounds__(256) void conv3x3(const short* __restrict__ inp,
                                               const short* __restrict__ wp,
                                               const float* __restrict__ scale,
                                               const float* __restrict__ shift,
                                               const float* __restrict__ w2f,
                                               short* __restrict__ outb,
                                               float* __restrict__ logits) {
  __shared__ short a_sm[128 * 32];
  __shared__ short b_sm[128 * 32];
  const int t = threadIdx.x;
  const int wv = t >> 6, lane = t & 63;
  const int l15 = lane & 15, quad = lane >> 4;
  const int tile = blockIdx.x;
  const int img = tile >> 7;
  const int h = tile & 127;
  const int nblk = blockIdx.y;
  const int m0 = (wv & 1) << 6;
  const int n0 = (wv >> 1) << 6;

  f32x4 acc[4][4];
#pragma unroll
  for (int i = 0; i < 4; ++i)
#pragma unroll
    for (int j = 0; j < 4; ++j) {
      acc[i][j][0] = 0.f; acc[i][j][1] = 0.f;
      acc[i][j][2] = 0.f; acc[i][j][3] = 0.f;
    }

  for (int tap = 0; tap < 9; ++tap) {
    const int dh = tap / 3 - 1, dw = tap % 3 - 1;
    const int hy = h + dh;
    if (hy < 0 || hy > 127) continue;  // block-uniform row-pad skip
    const size_t arow = ((size_t)(img * 128 + hy)) * WPITCH;
    const short* wtap = wp + ((size_t)(tap * 256 + nblk * 128)) * 256;

    for (int c0 = 0; c0 < 256; c0 += 32) {
      __syncthreads();
      // stage A: rows = w (padded cols make all lanes in-bounds: full exec)
#pragma unroll
      for (int j = 0; j < 2; ++j) {
        const int mrow = (j << 6) + (t >> 2);
        const int cc = t & 3;
        gll16(inp + (arow + mrow + dw + 1) * 256 + c0 + cc * 8,
              a_sm + ((size_t)((j << 8) + t)) * 8);
      }
      // stage B: rows = co
#pragma unroll
      for (int j = 0; j < 2; ++j) {
        const int nrow = (j << 6) + (t >> 2);
        const int cc = t & 3;
        gll16(wtap + (size_t)nrow * 256 + c0 + cc * 8,
              b_sm + ((size_t)((j << 8) + t)) * 8);
      }
      __syncthreads();  // vmcnt(0) drain lands the LDS writes

      bf16x8 af[4], bfr[4];
#pragma unroll
      for (int i = 0; i < 4; ++i)
        af[i] = *(const bf16x8*)(a_sm + (m0 + i * 16 + l15) * 32 + quad * 8);
#pragma unroll
      for (int i = 0; i < 4; ++i)
        bfr[i] = *(const bf16x8*)(b_sm + (n0 + i * 16 + l15) * 32 + quad * 8);
#pragma unroll
      for (int i = 0; i < 4; ++i)
#pragma unroll
        for (int j = 0; j < 4; ++j)
          acc[i][j] = __builtin_amdgcn_mfma_f32_16x16x32_bf16(af[i], bfr[j],
                                                              acc[i][j], 0, 0, 0);
    }
  }

  // C/D map: col = lane&15, row = quad*4 + reg
  float sc[4], sh[4], wf[4];
#pragma unroll
  for (int j = 0; j < 4; ++j) {
    const int co = nblk * 128 + n0 + j * 16 + l15;
    sc[j] = scale[co];
    sh[j] = shift[co];
    if (OUT_LOGITS) wf[j] = w2f[co];
  }
  if (OUT_LOGITS) {
    float* lrow = logits + ((size_t)img << 14) + (h << 7);
#pragma unroll
    for (int i = 0; i < 4; ++i) {
#pragma unroll
      for (int r = 0; r < 4; ++r) {
        float part = 0.f;
#pragma unroll
        for (int j = 0; j < 4; ++j) {
          float v = fmaxf(acc[i][j][r] * sc[j] + sh[j], 0.f);
          part += v * wf[j];
        }
        part += __shfl_xor(part, 1);
        part += __shfl_xor(part, 2);
        part += __shfl_xor(part, 4);
        part += __shfl_xor(part, 8);
        if (l15 == 0)
          atomicAdd(&lrow[m0 + i * 16 + quad * 4 + r], part);
      }
    }
  } else {
    const size_t obase = ((size_t)(img * 128 + h)) * WPITCH + 1;
#pragma unroll
    for (int i = 0; i < 4; ++i) {
#pragma unroll
      for (int j = 0; j < 4; ++j) {
        const int co = nblk * 128 + n0 + j * 16 + l15;
#pragma unroll
        for (int r = 0; r < 4; ++r) {
          const int m = m0 + i * 16 + quad * 4 + r;
          float v = fmaxf(acc[i][j][r] * sc[j] + sh[j], 0.f);
          outb[(obase + m) * 256 + co] = f2bf(v);
        }
      }
    }
  }
}

// --- radix-select: all elements with key >= K*, where K* is the exact
// 32-bit key threshold of rank 128. One block per batch. ---------------------
__global__ __launch_bounds__(1024) void topk_radix(const float* __restrict__ logits,
                                                   int* __restrict__ cand,
                                                   int* __restrict__ cnt_out) {
  __shared__ int hist[2048];
  __shared__ int wsum[16];
  __shared__ unsigned sel_bin;
  __shared__ int sel_above;
  __shared__ int cntr;
  const int b = blockIdx.x, t = threadIdx.x;
  const int lane = t & 63, wid = t >> 6;
  const float* L = logits + (size_t)b * HW;
  const int base = t * 16;
  unsigned kv[16];
#pragma unroll
  for (int i = 0; i < 4; ++i) {
    float4 v = *(const float4*)(L + base + i * 4);
    float f4[4] = {v.x, v.y, v.z, v.w};
#pragma unroll
    for (int j = 0; j < 4; ++j) {
      unsigned u = __float_as_uint(f4[j]);
      kv[i * 4 + j] = u ^ (((unsigned)((int)u >> 31)) | 0x80000000u);
    }
  }
  unsigned prefix = 0, pmask = 0;
  int need = 128;
  const int shifts[3] = {21, 10, 0};
  const int nbs[3] = {2048, 2048, 1024};

  for (int lev = 0; lev < 3; ++lev) {
    const int shift = shifts[lev];
    const int nb = nbs[lev];
    hist[t] = 0;
    hist[t + 1024] = 0;
    __syncthreads();
#pragma unroll
    for (int i = 0; i < 16; ++i)
      if ((kv[i] & pmask) == prefix)
        atomicAdd(&hist[(kv[i] >> shift) & (nb - 1)], 1);
    __syncthreads();
    // descending chunk ownership: thread t owns bins [bin_hi-cs+1 .. bin_hi]
    const int cs = nb >> 10;  // 2 or 1
    const int bin_hi = nb - 1 - t * cs;
    const int c_hi = hist[bin_hi];
    const int c_lo = (cs == 2) ? hist[bin_hi - 1] : 0;
    const int s = c_hi + c_lo;
    // exclusive scan over thread order
    int inc = s;
    for (int off = 1; off < 64; off <<= 1) {
      int nbr = __shfl_up(inc, off);
      if (lane >= off) inc += nbr;
    }
    if (lane == 63) wsum[wid] = inc;
    __syncthreads();
    if (wid == 0) {
      int wv = (lane < 16) ? wsum[lane] : 0;
      for (int off = 1; off < 16; off <<= 1) {
        int nbr = __shfl_up(wv, off);
        if (lane >= off) wv += nbr;
      }
      if (lane < 16) wsum[lane] = wv;
    }
    __syncthreads();
    const int excl = inc - s + (wid ? wsum[wid - 1] : 0);
    if (excl < need && need <= excl + s) {  // exactly one thread
      if (need <= excl + c_hi) {
        sel_bin = (unsigned)bin_hi;
        sel_above = excl;
      } else {
        sel_bin = (unsigned)(bin_hi - 1);
        sel_above = excl + c_hi;
      }
    }
    __syncthreads();
    prefix |= sel_bin << shift;
    pmask |= ((unsigned)(nb - 1)) << shift;
    need -= sel_above;
    __syncthreads();
  }
  // prefix == K* (exact rank-128 key). Select key >= K* (>=128 elems).
  if (t == 0) cntr = 0;
  __syncthreads();
#pragma unroll
  for (int i = 0; i < 16; ++i) {
    if (kv[i] >= prefix) {
      int p = atomicAdd(&cntr, 1);
      if (p < CCAP) cand[b * CCAP + p] = base + i;
    }
  }
  __syncthreads();
  if (t == 0) cnt_out[b] = (cntr < CCAP) ? cntr : CCAP;
}

// --- EXACT fp32 rescore, G=2 candidates per block ---------------------------
// logit(s) = 1x1( relu(bn2( conv2( relu(bn1( conv1(x) )) ))) )[s], all fp32.
// Weights [tap][ci][co] read once per ci and applied to BOTH candidates:
// halves L2 weight traffic and doubles FMA per load vs G=1.
#define XPS 26   // xp LDS stride (float2-aligned, low write conflicts)
#define F9S 12   // f9 LDS stride (float4-aligned)
__global__ __launch_bounds__(256) void rescore(const float* __restrict__ x,
                                               const float* __restrict__ w1t,
                                               const float* __restrict__ w2t,
                                               const float* __restrict__ bnp,
                                               const float* __restrict__ b2,
                                               const int* __restrict__ cand,
                                               const int* __restrict__ cnt,
                                               float* __restrict__ exlog) {
  const int b = blockIdx.y, t = threadIdx.x;
  const int n = cnt[b];
  const int c0 = blockIdx.x * 2;
  if (c0 >= n) return;  // block-uniform early exit (before any barrier)
  const int c1 = c0 + 1;
  const bool has1 = (c1 < n);
  __shared__ float xp_sm[2][256 * XPS];
  __shared__ float f9_sm[2][256 * F9S];
  __shared__ float red[2][4];
  const int s0 = cand[b * CCAP + c0];
  const int s1 = has1 ? cand[b * CCAP + c1] : s0;

  // stage both 5x5 patches: thread t = channel t
  {
    const float* xc = x + (((size_t)(b * 256 + t)) << 14);
    const int hh[2] = {s0 >> 7, s1 >> 7};
    const int ww[2] = {s0 & 127, s1 & 127};
#pragma unroll
    for (int g = 0; g < 2; ++g) {
#pragma unroll
      for (int p = 0; p < 25; ++p) {
        int hy = hh[g] + p / 5 - 2, wx = ww[g] + p % 5 - 2;
        float v = 0.f;
        if (hy >= 0 && hy < 128 && wx >= 0 && wx < 128) v = xc[(hy << 7) + wx];
        xp_sm[g][t * XPS + p] = v;
      }
    }
  }
  __syncthreads();

  // conv1: thread t = co, 9 output positions x 2 candidates per weight read
  float aA[9], aB[9];
#pragma unroll
  for (int p = 0; p < 9; ++p) { aA[p] = 0.f; aB[p] = 0.f; }
  for (int ci = 0; ci < 256; ++ci) {
    float w9[9];
    const float* wr = w1t + (size_t)ci * 256 + t;
#pragma unroll
    for (int k = 0; k < 9; ++k) w9[k] = wr[(size_t)k * 65536];
#pragma unroll
    for (int g = 0; g < 2; ++g) {
      float xp[25];
      const float2* xr = (const float2*)(xp_sm[g] + ci * XPS);
#pragma unroll
      for (int q = 0; q < 12; ++q) {
        float2 v = xr[q];
        xp[q * 2] = v.x;
        xp[q * 2 + 1] = v.y;
      }
      xp[24] = xp_sm[g][ci * XPS + 24];
      float* ag = g ? aB : aA;
#pragma unroll
      for (int py = 0; py < 3; ++py)
#pragma unroll
        for (int px = 0; px < 3; ++px)
#pragma unroll
          for (int ky = 0; ky < 3; ++ky)
#pragma unroll
            for (int kx = 0; kx < 3; ++kx)
              ag[py * 3 + px] += w9[ky * 3 + kx] * xp[(py + ky) * 5 + px + kx];
    }
  }
  {
    const float sc1 = bnp[t], sh1 = bnp[256 + t];
#pragma unroll
    for (int p = 0; p < 9; ++p) {
      f9_sm[0][t * F9S + p] = fmaxf(aA[p] * sc1 + sh1, 0.f);
      f9_sm[1][t * F9S + p] = fmaxf(aB[p] * sc1 + sh1, 0.f);
    }
  }
  __syncthreads();

  // conv2 at s: thread t = co2, both candidates per weight read
  float accA = 0.f, accB = 0.f;
  for (int ci = 0; ci < 256; ++ci) {
    float w9[9];
    const float* wr = w2t + (size_t)ci * 256 + t;
#pragma unroll
    for (int k = 0; k < 9; ++k) w9[k] = wr[(size_t)k * 65536];
#pragma unroll
    for (int g = 0; g < 2; ++g) {
      float f9[12];
      const float4* fr = (const float4*)(f9_sm[g] + ci * F9S);
#pragma unroll
      for (int q = 0; q < 3; ++q) {
        float4 v = fr[q];
        f9[q * 4 + 0] = v.x; f9[q * 4 + 1] = v.y;
        f9[q * 4 + 2] = v.z; f9[q * 4 + 3] = v.w;
      }
      float s = 0.f;
#pragma unroll
      for (int k = 0; k < 9; ++k) s += w9[k] * f9[k];
      if (g) accB += s; else accA += s;
    }
  }
  const float sc2 = bnp[512 + t], sh2 = bnp[768 + t], wf = bnp[1024 + t];
  float pA = fmaxf(accA * sc2 + sh2, 0.f) * wf;
  float pB = fmaxf(accB * sc2 + sh2, 0.f) * wf;
  for (int off = 32; off; off >>= 1) {
    pA += __shfl_xor(pA, off);
    pB += __shfl_xor(pB, off);
  }
  if ((t & 63) == 0) {
    red[0][t >> 6] = pA;
    red[1][t >> 6] = pB;
  }
  __syncthreads();
  if (t == 0) {
    exlog[b * CCAP + c0] = red[0][0] + red[0][1] + red[0][2] + red[0][3] + b2[0];
    if (has1)
      exlog[b * CCAP + c1] = red[1][0] + red[1][1] + red[1][2] + red[1][3] + b2[0];
  }
}

// --- rank-sort exact logits, keep top-100 (jax tie-break: lower idx) --------
__global__ __launch_bounds__(CCAP) void final_topk(const float* __restrict__ exlog,
                                                   const int* __restrict__ cand,
                                                   const int* __restrict__ cnt,
                                                   int* __restrict__ tidx,
                                                   float* __restrict__ tlog) {
  const int b = blockIdx.x, t = threadIdx.x;
  __shared__ float v[CCAP];
  __shared__ int si[CCAP];
  const int n = cnt[b];
  float mv = (t < n) ? exlog[b * CCAP + t] : -3.0e38f;
  int s = (t < n) ? cand[b * CCAP + t] : 0x7FFFFFFF;
  v[t] = mv;
  si[t] = s;
  __syncthreads();
  int rank = 0;
  for (int j = 0; j < CCAP; ++j) {
    float vj = v[j];
    int sj = si[j];
    if (vj > mv || (vj == mv && sj < s)) ++rank;
  }
  if (t < n && rank < 100) {
    tidx[b * 100 + rank] = s;
    tlog[b * 100 + rank] = mv;
  }
}

// --- fused FFN + LN + heads + anchor (fp32 out), one block per query --------
__global__ __launch_bounds__(256) void head_kern(
    const short* __restrict__ featb, const int* __restrict__ tidx,
    const float* __restrict__ tlog, const float* __restrict__ tmpl,
    const float* __restrict__ w1, const float* __restrict__ b1,
    const float* __restrict__ lng, const float* __restrict__ lnb,
    const float* __restrict__ w2, const float* __restrict__ b2,
    const float* __restrict__ zw, const float* __restrict__ zb,
    const float* __restrict__ dmw, const float* __restrict__ dmb,
    const float* __restrict__ yw, const float* __restrict__ yb,
    const float* __restrict__ vw, const float* __restrict__ vb,
    float* __restrict__ out) {
  const int blk = blockIdx.x;  // 400
  const int b = blk / 100, q = blk % 100;
  const int t = threadIdx.x;
  const int lane = t & 63, wid = t >> 6;
  __shared__ float g[256];
  __shared__ float sx[256];
  __shared__ float red[4];
  __shared__ float heads[8];

  const int s = tidx[b * 100 + q];
  const float score = 1.f / (1.f + expf(-tlog[b * 100 + q]));
  const int ys = s >> 7, xs = s & 127;

  g[t] = bf2f(featb[(((size_t)(b * 128 + ys)) * WPITCH + xs + 1) * 256 + t]);
  __syncthreads();

  float x = b1[t];
  {
    const float* wr = w1 + (size_t)t * 256;
    for (int i = 0; i < 256; i += 4) {
      float4 wv = *(const float4*)(wr + i);
      x += g[i] * wv.x + g[i + 1] * wv.y + g[i + 2] * wv.z + g[i + 3] * wv.w;
    }
  }
  float sum = x;
  for (int off = 32; off; off >>= 1) sum += __shfl_xor(sum, off);
  if (lane == 0) red[wid] = sum;
  __syncthreads();
  float mu = (red[0] + red[1] + red[2] + red[3]) * (1.f / 256.f);
  __syncthreads();
  float d = x - mu;
  float q2 = d * d;
  for (int off = 32; off; off >>= 1) q2 += __shfl_xor(q2, off);
  if (lane == 0) red[wid] = q2;
  __syncthreads();
  float var = (red[0] + red[1] + red[2] + red[3]) * (1.f / 256.f);
  float xn = d * (1.f / sqrtf(var + 1e-5f)) * lng[t] + lnb[t];
  xn = fmaxf(xn, 0.f);
  sx[t] = xn;
  __syncthreads();
  float pf = b2[t];
  {
    const float* wr = w2 + (size_t)t * 256;
    for (int i = 0; i < 256; i += 4) {
      float4 wv = *(const float4*)(wr + i);
      pf += sx[i] * wv.x + sx[i + 1] * wv.y + sx[i + 2] * wv.z + sx[i + 3] * wv.w;
    }
  }
  pf *= (1.f + score);
  out[(size_t)(b * 100 + q) * 256 + t] = pf;

  const int k = t >> 5, l = t & 31;
  const float* hw;
  float hb;
  if (k == 0)      { hw = zw;                 hb = zb[0]; }
  else if (k < 4)  { hw = dmw + (k - 1) * 256; hb = dmb[k - 1]; }
  else if (k < 6)  { hw = yw + (k - 4) * 256;  hb = yb[k - 4]; }
  else             { hw = vw + (k - 6) * 256;  hb = vb[k - 6]; }
  float hp = 0.f;
#pragma unroll
  for (int r = 0; r < 8; ++r) {
    int i = l + r * 32;
    hp += g[i] * hw[i];
  }
  for (int off = 16; off; off >>= 1) hp += __shfl_xor(hp, off);
  if (l == 0) heads[k] = hp + hb;
  __syncthreads();

  if (t == 0) {
    const float* pa = tmpl + ((size_t)b * 900 + q) * 11;
    float p[11];
#pragma unroll
    for (int i = 0; i < 11; ++i) p[i] = pa[i];
    float a[11];
    a[0] = ((float)xs + 0.5f) * 0.8f - 51.2f;
    a[1] = ((float)ys + 0.5f) * 0.8f - 51.2f;
    a[2] = p[2] + 0.5f * heads[0];
#pragma unroll
    for (int i = 0; i < 3; ++i)
      a[3 + i] = p[3 + i] + 0.2f * fminf(fmaxf(heads[1 + i], -1.f), 1.f);
    float t0 = tanhf(heads[4]), t1 = tanhf(heads[5]);
    float nrm = fmaxf(sqrtf(t0 * t0 + t1 * t1), 1e-6f);
    a[6] = 0.7f * p[6] + 0.3f * t0 / nrm;
    a[7] = 0.7f * p[7] + 0.3f * t1 / nrm;
    a[8] = p[8] + 0.2f * fminf(fmaxf(heads[6], -2.f), 2.f);
    a[9] = p[9] + 0.2f * fminf(fmaxf(heads[7], -2.f), 2.f);
    a[10] = p[10];
    float* oa = out + 102400 + (size_t)(b * 100 + q) * 11;
#pragma unroll
    for (int i = 0; i < 11; ++i) oa[i] = a[i];
    out[106800 + b * 100 + q] = score;
  }
}

extern "C" void kernel_launch(void* const* d_in, const int* in_sizes, int n_in,
                              void* d_out, int out_size, void* d_ws, size_t ws_size,
                              hipStream_t stream) {
  (void)in_sizes; (void)n_in; (void)out_size; (void)ws_size;
  char* ws = (char*)d_ws;
  short* xn     = (short*)(ws + WSO_XN);
  short* featb  = (short*)(ws + WSO_FEATB);
  short* wp1    = (short*)(ws + WSO_WP1);
  short* wp2    = (short*)(ws + WSO_WP2);
  float* bnp    = (float*)(ws + WSO_BNP);
  float* logits = (float*)(ws + WSO_LOG);
  int*   cand   = (int*)(ws + WSO_CAND);
  int*   cnt    = (int*)(ws + WSO_CNT);
  float* exl    = (float*)(ws + WSO_EXL);
  int*   tidx   = (int*)(ws + WSO_TIDX);
  float* tlog   = (float*)(ws + WSO_TLOG);
  float* w1t    = (float*)(ws + WSO_W1T);
  float* w2t    = (float*)(ws + WSO_W2T);

  const float* bev = (const float*)d_in[0];

  wreorder<<<2304, 256, 0, stream>>>((const float*)d_in[2], wp1);
  wreorder<<<2304, 256, 0, stream>>>((const float*)d_in[7], wp2);
  wtrans<<<2304, 256, 0, stream>>>((const float*)d_in[2], w1t);
  wtrans<<<2304, 256, 0, stream>>>((const float*)d_in[7], w2t);
  bnprep<<<1, 256, 0, stream>>>(
      (const float*)d_in[3], (const float*)d_in[4], (const float*)d_in[5],
      (const float*)d_in[6], (const float*)d_in[8], (const float*)d_in[9],
      (const float*)d_in[10], (const float*)d_in[11], (const float*)d_in[12], bnp);
  padzero<<<1024, 256, 0, stream>>>(xn, featb);
  loginit<<<256, 256, 0, stream>>>(logits, (const float*)d_in[13]);
  nchw2nhwc<<<dim3(256, 4, 4), 256, 0, stream>>>(bev, xn);
  conv3x3<0><<<dim3(512, 2), 256, 0, stream>>>(xn, wp1, bnp, bnp + 256,
                                               nullptr, featb, nullptr);
  conv3x3<1><<<dim3(512, 2), 256, 0, stream>>>(featb, wp2, bnp + 512, bnp + 768,
                                               bnp + 1024, nullptr, logits);
  topk_radix<<<4, 1024, 0, stream>>>(logits, cand, cnt);
  rescore<<<dim3(96, 4), 256, 0, stream>>>(bev, w1t, w2t, bnp,
                                           (const float*)d_in[13], cand, cnt,
                                           exl);
  final_topk<<<4, CCAP, 0, stream>>>(exl, cand, cnt, tidx, tlog);
  head_kern<<<400, 256, 0, stream>>>(
      featb, tidx, tlog, (const float*)d_in[1],
      (const float*)d_in[14], (const float*)d_in[15], (const float*)d_in[16],
      (const float*)d_in[17], (const float*)d_in[18], (const float*)d_in[19],
      (const float*)d_in[20], (const float*)d_in[21], (const float*)d_in[22],
      (const float*)d_in[23], (const float*)d_in[24], (const float*)d_in[25],
      (const float*)d_in[26], (const float*)d_in[27], (float*)d_out);
}

// Round 6
// 704.322 us; speedup vs baseline: 1.0398x; 1.0398x over previous
//
#include <hip/hip_runtime.h>
#include <math.h>

// ---------------------------------------------------------------------------
// LiDARPriorQueryGenerator — MI355X (gfx950). FP32 I/O per reference dtypes.
// prep(w-reorder bf16, [ci][tap][co] fp32 reorder, bn-fold) -> NHWC bf16
// (W padded 130) -> conv1 MFMA -> featb bf16 -> conv2 MFMA + fused 1x1 score
// (atomicAdd logits) -> RADIX-SELECT top>=128 -> patchstage (uniform patches
// to global) -> EXACT fp32 rescore (scalar-pipe patches + coalesced weights)
// -> final top-100 -> fused FFN/LN/heads/anchor.
// ---------------------------------------------------------------------------

typedef __attribute__((ext_vector_type(8))) short bf16x8;
typedef __attribute__((ext_vector_type(4))) float f32x4;

#define HW 16384
#define WPITCH 130   // padded width: col 0 and 129 are zero pads
#define CCAP 192     // candidate cap (count(key>=K*) typically 128..~132)
#define PSTR 28      // patch buffer stride (floats) per (cand, ci)
// workspace byte offsets
#define WSO_XN    0ULL           // bf16 NHWC padded input; LATER pbuf alias
#define WSO_FEATB 34078720ULL    // bf16 NHWC padded feat   (34,078,720)
#define WSO_WP1   68157440ULL    // bf16 [9][256][256] shared_w
#define WSO_WP2   69337088ULL    // bf16 [9][256][256] obj_w1
#define WSO_BNP   70516736ULL    // fp32 scale1,shift1,scale2,shift2,w2f (1280)
#define WSO_LOG   70521856ULL    // fp32 65536 logits
#define WSO_CAND  70784000ULL    // int 4*CCAP
#define WSO_CNT   70787072ULL    // int 4 (+pad)
#define WSO_EXL   70787136ULL    // fp32 4*CCAP
#define WSO_TIDX  70790208ULL    // int 4*100
#define WSO_TLOG  70791808ULL    // fp32 4*100
#define WSO_W1N   70793408ULL    // fp32 [ci][tap][co] shared_w (2,359,296)
#define WSO_W2N   73152704ULL    // fp32 [ci][tap][co] obj_w1   (2,359,296)
#define WSO_PBUF  WSO_XN         // fp32 [b][cand][ci][PSTR] patches (22 MB),
                                 // aliases xn (dead after conv2)

__device__ __forceinline__ float bf2f(short s) {
  return __uint_as_float(((unsigned)(unsigned short)s) << 16);
}
__device__ __forceinline__ short f2bf(float f) {  // RNE
  unsigned u = __float_as_uint(f);
  u += 0x7fffu + ((u >> 16) & 1u);
  return (short)(u >> 16);
}
__device__ __forceinline__ void gll16(const void* g, void* l) {
  __builtin_amdgcn_global_load_lds(
      (const __attribute__((address_space(1))) void*)g,
      (__attribute__((address_space(3))) void*)l, 16, 0, 0);
}

// --- prep: reorder conv weights (co,ci,kh,kw) f32 -> [tap][co][ci] bf16 -----
__global__ void wreorder(const float* __restrict__ src, short* __restrict__ dst) {
  int i = blockIdx.x * 256 + threadIdx.x;  // grid 2304
  int ci = i & 255;
  int r = i >> 8;
  int co = r & 255;
  int tap = r >> 8;
  dst[i] = f2bf(src[(co * 256 + ci) * 9 + tap]);
}

// --- prep: reorder conv weights f32 -> [ci][tap][co] fp32 (for rescore) -----
__global__ void wtrans2(const float* __restrict__ src, float* __restrict__ dst) {
  int i = blockIdx.x * 256 + threadIdx.x;  // grid 2304
  int co = i & 255;
  int r = i >> 8;       // r = ci*9 + k
  int ci = r / 9;
  int k = r % 9;
  dst[i] = src[(co * 256 + ci) * 9 + k];
}

// --- prep: fold BN into scale/shift (fp32-exact), copy w2 -------------------
__global__ void bnprep(const float* g1, const float* b1, const float* m1,
                       const float* v1, const float* g2, const float* b2,
                       const float* m2, const float* v2, const float* w2,
                       float* __restrict__ out) {
  int c = threadIdx.x;
  float s1 = g1[c] / sqrtf(v1[c] + 1e-5f);
  out[c] = s1;
  out[256 + c] = b1[c] - m1[c] * s1;
  float s2 = g2[c] / sqrtf(v2[c] + 1e-5f);
  out[512 + c] = s2;
  out[768 + c] = b2[c] - m2[c] * s2;
  out[1024 + c] = w2[c];
}

// --- zero the W-pad columns of xn and featb ---------------------------------
__global__ void padzero(short* __restrict__ xn, short* __restrict__ featb) {
  int i = blockIdx.x * 256 + threadIdx.x;  // grid 1024 -> 262144
  int c = i & 255;
  int r = i >> 8;            // 0..1023 : nh(512) x side(2)
  int nh = r >> 1;
  int side = r & 1;
  size_t off = ((size_t)nh * WPITCH + (side ? 129 : 0)) * 256 + c;
  xn[off] = 0;
  featb[off] = 0;
}

// --- logits init to 1x1 bias ------------------------------------------------
__global__ void loginit(float* __restrict__ logits, const float* __restrict__ b2) {
  logits[blockIdx.x * 256 + threadIdx.x] = b2[0];
}

// --- NCHW f32 -> NHWC bf16 (padded W) ---------------------------------------
__global__ __launch_bounds__(256) void nchw2nhwc(const float* __restrict__ in,
                                                 short* __restrict__ out) {
  __shared__ short tl[64 * 66];
  int n = blockIdx.z, c0 = blockIdx.y * 64, s0 = blockIdx.x * 64;
  int sl = threadIdx.x & 63, cl = threadIdx.x >> 6;
  for (int p = 0; p < 16; ++p) {
    int c = cl + p * 4;
    tl[c * 66 + sl] = f2bf(in[(((size_t)(n * 256 + c0 + c)) << 14) + s0 + sl]);
  }
  __syncthreads();
  int co = threadIdx.x & 63, so = threadIdx.x >> 6;
  for (int p = 0; p < 16; ++p) {
    int S = s0 + so + p * 4;
    int h = S >> 7, w = S & 127;
    out[(((size_t)(n * 128 + h)) * WPITCH + w + 1) * 256 + c0 + co] =
        tl[co * 66 + (so + p * 4)];
  }
}

// --- 3x3 conv + BN + ReLU via MFMA; OUT_LOGITS fuses the 1x1 score ----------
template <int OUT_LOGITS>
__global__ __launch_bounds__(256) void conv3x3(const short* __restrict__ inp,
                                               const short* __restrict__ wp,
                                               const float* __restrict__ scale,
                                               const float* __restrict__ shift,
                                               const float* __restrict__ w2f,
                                               short* __restrict__ outb,
                                               float* __restrict__ logits) {
  __shared__ short a_sm[128 * 32];
  __shared__ short b_sm[128 * 32];
  const int t = threadIdx.x;
  const int wv = t >> 6, lane = t & 63;
  const int l15 = lane & 15, quad = lane >> 4;
  const int tile = blockIdx.x;
  const int img = tile >> 7;
  const int h = tile & 127;
  const int nblk = blockIdx.y;
  const int m0 = (wv & 1) << 6;
  const int n0 = (wv >> 1) << 6;

  f32x4 acc[4][4];
#pragma unroll
  for (int i = 0; i < 4; ++i)
#pragma unroll
    for (int j = 0; j < 4; ++j) {
      acc[i][j][0] = 0.f; acc[i][j][1] = 0.f;
      acc[i][j][2] = 0.f; acc[i][j][3] = 0.f;
    }

  for (int tap = 0; tap < 9; ++tap) {
    const int dh = tap / 3 - 1, dw = tap % 3 - 1;
    const int hy = h + dh;
    if (hy < 0 || hy > 127) continue;  // block-uniform row-pad skip
    const size_t arow = ((size_t)(img * 128 + hy)) * WPITCH;
    const short* wtap = wp + ((size_t)(tap * 256 + nblk * 128)) * 256;

    for (int c0 = 0; c0 < 256; c0 += 32) {
      __syncthreads();
      // stage A: rows = w (padded cols make all lanes in-bounds: full exec)
#pragma unroll
      for (int j = 0; j < 2; ++j) {
        const int mrow = (j << 6) + (t >> 2);
        const int cc = t & 3;
        gll16(inp + (arow + mrow + dw + 1) * 256 + c0 + cc * 8,
              a_sm + ((size_t)((j << 8) + t)) * 8);
      }
      // stage B: rows = co
#pragma unroll
      for (int j = 0; j < 2; ++j) {
        const int nrow = (j << 6) + (t >> 2);
        const int cc = t & 3;
        gll16(wtap + (size_t)nrow * 256 + c0 + cc * 8,
              b_sm + ((size_t)((j << 8) + t)) * 8);
      }
      __syncthreads();  // vmcnt(0) drain lands the LDS writes

      bf16x8 af[4], bfr[4];
#pragma unroll
      for (int i = 0; i < 4; ++i)
        af[i] = *(const bf16x8*)(a_sm + (m0 + i * 16 + l15) * 32 + quad * 8);
#pragma unroll
      for (int i = 0; i < 4; ++i)
        bfr[i] = *(const bf16x8*)(b_sm + (n0 + i * 16 + l15) * 32 + quad * 8);
#pragma unroll
      for (int i = 0; i < 4; ++i)
#pragma unroll
        for (int j = 0; j < 4; ++j)
          acc[i][j] = __builtin_amdgcn_mfma_f32_16x16x32_bf16(af[i], bfr[j],
                                                              acc[i][j], 0, 0, 0);
    }
  }

  // C/D map: col = lane&15, row = quad*4 + reg
  float sc[4], sh[4], wf[4];
#pragma unroll
  for (int j = 0; j < 4; ++j) {
    const int co = nblk * 128 + n0 + j * 16 + l15;
    sc[j] = scale[co];
    sh[j] = shift[co];
    if (OUT_LOGITS) wf[j] = w2f[co];
  }
  if (OUT_LOGITS) {
    float* lrow = logits + ((size_t)img << 14) + (h << 7);
#pragma unroll
    for (int i = 0; i < 4; ++i) {
#pragma unroll
      for (int r = 0; r < 4; ++r) {
        float part = 0.f;
#pragma unroll
        for (int j = 0; j < 4; ++j) {
          float v = fmaxf(acc[i][j][r] * sc[j] + sh[j], 0.f);
          part += v * wf[j];
        }
        part += __shfl_xor(part, 1);
        part += __shfl_xor(part, 2);
        part += __shfl_xor(part, 4);
        part += __shfl_xor(part, 8);
        if (l15 == 0)
          atomicAdd(&lrow[m0 + i * 16 + quad * 4 + r], part);
      }
    }
  } else {
    const size_t obase = ((size_t)(img * 128 + h)) * WPITCH + 1;
#pragma unroll
    for (int i = 0; i < 4; ++i) {
#pragma unroll
      for (int j = 0; j < 4; ++j) {
        const int co = nblk * 128 + n0 + j * 16 + l15;
#pragma unroll
        for (int r = 0; r < 4; ++r) {
          const int m = m0 + i * 16 + quad * 4 + r;
          float v = fmaxf(acc[i][j][r] * sc[j] + sh[j], 0.f);
          outb[(obase + m) * 256 + co] = f2bf(v);
        }
      }
    }
  }
}

// --- radix-select: all elements with key >= K*, where K* is the exact
// 32-bit key threshold of rank 128. One block per batch. ---------------------
__global__ __launch_bounds__(1024) void topk_radix(const float* __restrict__ logits,
                                                   int* __restrict__ cand,
                                                   int* __restrict__ cnt_out) {
  __shared__ int hist[2048];
  __shared__ int wsum[16];
  __shared__ unsigned sel_bin;
  __shared__ int sel_above;
  __shared__ int cntr;
  const int b = blockIdx.x, t = threadIdx.x;
  const int lane = t & 63, wid = t >> 6;
  const float* L = logits + (size_t)b * HW;
  const int base = t * 16;
  unsigned kv[16];
#pragma unroll
  for (int i = 0; i < 4; ++i) {
    float4 v = *(const float4*)(L + base + i * 4);
    float f4[4] = {v.x, v.y, v.z, v.w};
#pragma unroll
    for (int j = 0; j < 4; ++j) {
      unsigned u = __float_as_uint(f4[j]);
      kv[i * 4 + j] = u ^ (((unsigned)((int)u >> 31)) | 0x80000000u);
    }
  }
  unsigned prefix = 0, pmask = 0;
  int need = 128;
  const int shifts[3] = {21, 10, 0};
  const int nbs[3] = {2048, 2048, 1024};

  for (int lev = 0; lev < 3; ++lev) {
    const int shift = shifts[lev];
    const int nb = nbs[lev];
    hist[t] = 0;
    hist[t + 1024] = 0;
    __syncthreads();
#pragma unroll
    for (int i = 0; i < 16; ++i)
      if ((kv[i] & pmask) == prefix)
        atomicAdd(&hist[(kv[i] >> shift) & (nb - 1)], 1);
    __syncthreads();
    // descending chunk ownership: thread t owns bins [bin_hi-cs+1 .. bin_hi]
    const int cs = nb >> 10;  // 2 or 1
    const int bin_hi = nb - 1 - t * cs;
    const int c_hi = hist[bin_hi];
    const int c_lo = (cs == 2) ? hist[bin_hi - 1] : 0;
    const int s = c_hi + c_lo;
    // exclusive scan over thread order
    int inc = s;
    for (int off = 1; off < 64; off <<= 1) {
      int nbr = __shfl_up(inc, off);
      if (lane >= off) inc += nbr;
    }
    if (lane == 63) wsum[wid] = inc;
    __syncthreads();
    if (wid == 0) {
      int wv = (lane < 16) ? wsum[lane] : 0;
      for (int off = 1; off < 16; off <<= 1) {
        int nbr = __shfl_up(wv, off);
        if (lane >= off) wv += nbr;
      }
      if (lane < 16) wsum[lane] = wv;
    }
    __syncthreads();
    const int excl = inc - s + (wid ? wsum[wid - 1] : 0);
    if (excl < need && need <= excl + s) {  // exactly one thread
      if (need <= excl + c_hi) {
        sel_bin = (unsigned)bin_hi;
        sel_above = excl;
      } else {
        sel_bin = (unsigned)(bin_hi - 1);
        sel_above = excl + c_hi;
      }
    }
    __syncthreads();
    prefix |= sel_bin << shift;
    pmask |= ((unsigned)(nb - 1)) << shift;
    need -= sel_above;
    __syncthreads();
  }
  // prefix == K* (exact rank-128 key). Select key >= K* (>=128 elems).
  if (t == 0) cntr = 0;
  __syncthreads();
#pragma unroll
  for (int i = 0; i < 16; ++i) {
    if (kv[i] >= prefix) {
      int p = atomicAdd(&cntr, 1);
      if (p < CCAP) cand[b * CCAP + p] = base + i;
    }
  }
  __syncthreads();
  if (t == 0) cnt_out[b] = (cntr < CCAP) ? cntr : CCAP;
}

// --- stage zero-padded 5x5x256 patches to global (block-uniform layout) -----
// pbuf[((b*CCAP + c)*256 + ci)*PSTR + p], p = (dy+2)*5 + (dx+2)
__global__ __launch_bounds__(256) void patchstage(const float* __restrict__ x,
                                                  const int* __restrict__ cand,
                                                  const int* __restrict__ cnt,
                                                  float* __restrict__ pbuf) {
  const int c = blockIdx.x, b = blockIdx.y, t = threadIdx.x;
  if (c >= cnt[b]) return;
  const int s = cand[b * CCAP + c];
  const int h0 = s >> 7, w0 = s & 127;
  const float* xc = x + (((size_t)(b * 256 + t)) << 14);
  float* pc = pbuf + ((size_t)((b * CCAP + c) * 256 + t)) * PSTR;
#pragma unroll
  for (int p = 0; p < 25; ++p) {
    int hy = h0 + p / 5 - 2, wx = w0 + p % 5 - 2;
    float v = 0.f;
    if (hy >= 0 && hy < 128 && wx >= 0 && wx < 128) v = xc[(hy << 7) + wx];
    pc[p] = v;
  }
}

// --- EXACT fp32 rescore: patches via the SCALAR pipe, weights [ci][tap][co] -
// logit(s) = 1x1( relu(bn2( conv2( relu(bn1( conv1(x) )) ))) )[s], all fp32.
// Patch pointer is blockIdx-derived (statically uniform) -> s_load_dwordx8;
// conv1 FMAs read the patch from SGPRs (zero LDS/VMEM broadcast cost).
__global__ __launch_bounds__(256) void rescore(const float* __restrict__ pbuf,
                                               const float* __restrict__ w1n,
                                               const float* __restrict__ w2n,
                                               const float* __restrict__ bnp,
                                               const float* __restrict__ b2,
                                               const int* __restrict__ cand,
                                               const int* __restrict__ cnt,
                                               float* __restrict__ exlog) {
  const int c = blockIdx.x, b = blockIdx.y, t = threadIdx.x;
  if (c >= cnt[b]) return;  // block-uniform early exit
  __shared__ float f9_sm[256 * 12];
  __shared__ float red[4];
  const float* pp = pbuf + ((size_t)(b * CCAP + c)) * (256 * PSTR);

  // conv1: thread t = co, 9 output positions
  float a9[9];
#pragma unroll
  for (int p = 0; p < 9; ++p) a9[p] = 0.f;
  for (int ci = 0; ci < 256; ++ci) {
    const float* pc = pp + ci * PSTR;  // uniform -> scalar loads
    float xp[25];
#pragma unroll
    for (int p = 0; p < 25; ++p) xp[p] = pc[p];
    const float* wr = w1n + (size_t)ci * 2304 + t;  // [ci][tap][co]
    float w9[9];
#pragma unroll
    for (int k = 0; k < 9; ++k) w9[k] = wr[k * 256];
#pragma unroll
    for (int py = 0; py < 3; ++py)
#pragma unroll
      for (int px = 0; px < 3; ++px)
#pragma unroll
        for (int ky = 0; ky < 3; ++ky)
#pragma unroll
          for (int kx = 0; kx < 3; ++kx)
            a9[py * 3 + px] += w9[ky * 3 + kx] * xp[(py + ky) * 5 + px + kx];
  }
  {
    const float sc1 = bnp[t], sh1 = bnp[256 + t];
#pragma unroll
    for (int p = 0; p < 9; ++p)
      f9_sm[t * 12 + p] = fmaxf(a9[p] * sc1 + sh1, 0.f);
  }
  __syncthreads();

  // conv2 at s: thread t = co2; f9 via broadcast b128 LDS reads
  float acc = 0.f;
  for (int ci = 0; ci < 256; ++ci) {
    float f9[12];
    const float4* fr = (const float4*)(f9_sm + ci * 12);
#pragma unroll
    for (int q = 0; q < 3; ++q) {
      float4 v = fr[q];
      f9[q * 4 + 0] = v.x; f9[q * 4 + 1] = v.y;
      f9[q * 4 + 2] = v.z; f9[q * 4 + 3] = v.w;
    }
    const float* wr = w2n + (size_t)ci * 2304 + t;
#pragma unroll
    for (int k = 0; k < 9; ++k) acc += wr[k * 256] * f9[k];
  }
  const float hv = fmaxf(acc * bnp[512 + t] + bnp[768 + t], 0.f);
  float p = hv * bnp[1024 + t];
  for (int off = 32; off; off >>= 1) p += __shfl_xor(p, off);
  if ((t & 63) == 0) red[t >> 6] = p;
  __syncthreads();
  if (t == 0) exlog[b * CCAP + c] = red[0] + red[1] + red[2] + red[3] + b2[0];
}

// --- rank-sort exact logits, keep top-100 (jax tie-break: lower idx) --------
__global__ __launch_bounds__(CCAP) void final_topk(const float* __restrict__ exlog,
                                                   const int* __restrict__ cand,
                                                   const int* __restrict__ cnt,
                                                   int* __restrict__ tidx,
                                                   float* __restrict__ tlog) {
  const int b = blockIdx.x, t = threadIdx.x;
  __shared__ float v[CCAP];
  __shared__ int si[CCAP];
  const int n = cnt[b];
  float mv = (t < n) ? exlog[b * CCAP + t] : -3.0e38f;
  int s = (t < n) ? cand[b * CCAP + t] : 0x7FFFFFFF;
  v[t] = mv;
  si[t] = s;
  __syncthreads();
  int rank = 0;
  for (int j = 0; j < CCAP; ++j) {
    float vj = v[j];
    int sj = si[j];
    if (vj > mv || (vj == mv && sj < s)) ++rank;
  }
  if (t < n && rank < 100) {
    tidx[b * 100 + rank] = s;
    tlog[b * 100 + rank] = mv;
  }
}

// --- fused FFN + LN + heads + anchor (fp32 out), one block per query --------
__global__ __launch_bounds__(256) void head_kern(
    const short* __restrict__ featb, const int* __restrict__ tidx,
    const float* __restrict__ tlog, const float* __restrict__ tmpl,
    const float* __restrict__ w1, const float* __restrict__ b1,
    const float* __restrict__ lng, const float* __restrict__ lnb,
    const float* __restrict__ w2, const float* __restrict__ b2,
    const float* __restrict__ zw, const float* __restrict__ zb,
    const float* __restrict__ dmw, const float* __restrict__ dmb,
    const float* __restrict__ yw, const float* __restrict__ yb,
    const float* __restrict__ vw, const float* __restrict__ vb,
    float* __restrict__ out) {
  const int blk = blockIdx.x;  // 400
  const int b = blk / 100, q = blk % 100;
  const int t = threadIdx.x;
  const int lane = t & 63, wid = t >> 6;
  __shared__ float g[256];
  __shared__ float sx[256];
  __shared__ float red[4];
  __shared__ float heads[8];

  const int s = tidx[b * 100 + q];
  const float score = 1.f / (1.f + expf(-tlog[b * 100 + q]));
  const int ys = s >> 7, xs = s & 127;

  g[t] = bf2f(featb[(((size_t)(b * 128 + ys)) * WPITCH + xs + 1) * 256 + t]);
  __syncthreads();

  float x = b1[t];
  {
    const float* wr = w1 + (size_t)t * 256;
    for (int i = 0; i < 256; i += 4) {
      float4 wv = *(const float4*)(wr + i);
      x += g[i] * wv.x + g[i + 1] * wv.y + g[i + 2] * wv.z + g[i + 3] * wv.w;
    }
  }
  float sum = x;
  for (int off = 32; off; off >>= 1) sum += __shfl_xor(sum, off);
  if (lane == 0) red[wid] = sum;
  __syncthreads();
  float mu = (red[0] + red[1] + red[2] + red[3]) * (1.f / 256.f);
  __syncthreads();
  float d = x - mu;
  float q2 = d * d;
  for (int off = 32; off; off >>= 1) q2 += __shfl_xor(q2, off);
  if (lane == 0) red[wid] = q2;
  __syncthreads();
  float var = (red[0] + red[1] + red[2] + red[3]) * (1.f / 256.f);
  float xn = d * (1.f / sqrtf(var + 1e-5f)) * lng[t] + lnb[t];
  xn = fmaxf(xn, 0.f);
  sx[t] = xn;
  __syncthreads();
  float pf = b2[t];
  {
    const float* wr = w2 + (size_t)t * 256;
    for (int i = 0; i < 256; i += 4) {
      float4 wv = *(const float4*)(wr + i);
      pf += sx[i] * wv.x + sx[i + 1] * wv.y + sx[i + 2] * wv.z + sx[i + 3] * wv.w;
    }
  }
  pf *= (1.f + score);
  out[(size_t)(b * 100 + q) * 256 + t] = pf;

  const int k = t >> 5, l = t & 31;
  const float* hw;
  float hb;
  if (k == 0)      { hw = zw;                 hb = zb[0]; }
  else if (k < 4)  { hw = dmw + (k - 1) * 256; hb = dmb[k - 1]; }
  else if (k < 6)  { hw = yw + (k - 4) * 256;  hb = yb[k - 4]; }
  else             { hw = vw + (k - 6) * 256;  hb = vb[k - 6]; }
  float hp = 0.f;
#pragma unroll
  for (int r = 0; r < 8; ++r) {
    int i = l + r * 32;
    hp += g[i] * hw[i];
  }
  for (int off = 16; off; off >>= 1) hp += __shfl_xor(hp, off);
  if (l == 0) heads[k] = hp + hb;
  __syncthreads();

  if (t == 0) {
    const float* pa = tmpl + ((size_t)b * 900 + q) * 11;
    float p[11];
#pragma unroll
    for (int i = 0; i < 11; ++i) p[i] = pa[i];
    float a[11];
    a[0] = ((float)xs + 0.5f) * 0.8f - 51.2f;
    a[1] = ((float)ys + 0.5f) * 0.8f - 51.2f;
    a[2] = p[2] + 0.5f * heads[0];
#pragma unroll
    for (int i = 0; i < 3; ++i)
      a[3 + i] = p[3 + i] + 0.2f * fminf(fmaxf(heads[1 + i], -1.f), 1.f);
    float t0 = tanhf(heads[4]), t1 = tanhf(heads[5]);
    float nrm = fmaxf(sqrtf(t0 * t0 + t1 * t1), 1e-6f);
    a[6] = 0.7f * p[6] + 0.3f * t0 / nrm;
    a[7] = 0.7f * p[7] + 0.3f * t1 / nrm;
    a[8] = p[8] + 0.2f * fminf(fmaxf(heads[6], -2.f), 2.f);
    a[9] = p[9] + 0.2f * fminf(fmaxf(heads[7], -2.f), 2.f);
    a[10] = p[10];
    float* oa = out + 102400 + (size_t)(b * 100 + q) * 11;
#pragma unroll
    for (int i = 0; i < 11; ++i) oa[i] = a[i];
    out[106800 + b * 100 + q] = score;
  }
}

extern "C" void kernel_launch(void* const* d_in, const int* in_sizes, int n_in,
                              void* d_out, int out_size, void* d_ws, size_t ws_size,
                              hipStream_t stream) {
  (void)in_sizes; (void)n_in; (void)out_size; (void)ws_size;
  char* ws = (char*)d_ws;
  short* xn     = (short*)(ws + WSO_XN);
  short* featb  = (short*)(ws + WSO_FEATB);
  short* wp1    = (short*)(ws + WSO_WP1);
  short* wp2    = (short*)(ws + WSO_WP2);
  float* bnp    = (float*)(ws + WSO_BNP);
  float* logits = (float*)(ws + WSO_LOG);
  int*   cand   = (int*)(ws + WSO_CAND);
  int*   cnt    = (int*)(ws + WSO_CNT);
  float* exl    = (float*)(ws + WSO_EXL);
  int*   tidx   = (int*)(ws + WSO_TIDX);
  float* tlog   = (float*)(ws + WSO_TLOG);
  float* w1n    = (float*)(ws + WSO_W1N);
  float* w2n    = (float*)(ws + WSO_W2N);
  float* pbuf   = (float*)(ws + WSO_PBUF);  // aliases xn (dead after conv2)

  const float* bev = (const float*)d_in[0];

  wreorder<<<2304, 256, 0, stream>>>((const float*)d_in[2], wp1);
  wreorder<<<2304, 256, 0, stream>>>((const float*)d_in[7], wp2);
  wtrans2<<<2304, 256, 0, stream>>>((const float*)d_in[2], w1n);
  wtrans2<<<2304, 256, 0, stream>>>((const float*)d_in[7], w2n);
  bnprep<<<1, 256, 0, stream>>>(
      (const float*)d_in[3], (const float*)d_in[4], (const float*)d_in[5],
      (const float*)d_in[6], (const float*)d_in[8], (const float*)d_in[9],
      (const float*)d_in[10], (const float*)d_in[11], (const float*)d_in[12], bnp);
  padzero<<<1024, 256, 0, stream>>>(xn, featb);
  loginit<<<256, 256, 0, stream>>>(logits, (const float*)d_in[13]);
  nchw2nhwc<<<dim3(256, 4, 4), 256, 0, stream>>>(bev, xn);
  conv3x3<0><<<dim3(512, 2), 256, 0, stream>>>(xn, wp1, bnp, bnp + 256,
                                               nullptr, featb, nullptr);
  conv3x3<1><<<dim3(512, 2), 256, 0, stream>>>(featb, wp2, bnp + 512, bnp + 768,
                                               bnp + 1024, nullptr, logits);
  topk_radix<<<4, 1024, 0, stream>>>(logits, cand, cnt);
  // xn is dead from here on; pbuf reuses its storage.
  patchstage<<<dim3(CCAP, 4), 256, 0, stream>>>(bev, cand, cnt, pbuf);
  rescore<<<dim3(CCAP, 4), 256, 0, stream>>>(pbuf, w1n, w2n, bnp,
                                             (const float*)d_in[13], cand, cnt,
                                             exl);
  final_topk<<<4, CCAP, 0, stream>>>(exl, cand, cnt, tidx, tlog);
  head_kern<<<400, 256, 0, stream>>>(
      featb, tidx, tlog, (const float*)d_in[1],
      (const float*)d_in[14], (const float*)d_in[15], (const float*)d_in[16],
      (const float*)d_in[17], (const float*)d_in[18], (const float*)d_in[19],
      (const float*)d_in[20], (const float*)d_in[21], (const float*)d_in[22],
      (const float*)d_in[23], (const float*)d_in[24], (const float*)d_in[25],
      (const float*)d_in[26], (const float*)d_in[27], (float*)d_out);
}

// Round 7
// 638.201 us; speedup vs baseline: 1.1475x; 1.1036x over previous
//
#include <hip/hip_runtime.h>
#include <math.h>

// ---------------------------------------------------------------------------
// LiDARPriorQueryGenerator — MI355X (gfx950). FP32 I/O per reference dtypes.
// prep(w-reorder bf16, [ci][tap][co] fp32 reorder, bn-fold) -> NHWC bf16
// (W padded 130) -> conv1 MFMA -> featb bf16 -> conv2 MFMA + fused 1x1 score
// (atomicAdd logits) -> RADIX-SELECT top>=128 -> patchstage (lane-remapped
// coalesced-ish gather) -> EXACT fp32 rescore (1024 thr, 4-way split-K,
// scalar-pipe patches) -> final top-100 -> fused FFN/LN/heads/anchor.
// ---------------------------------------------------------------------------

typedef __attribute__((ext_vector_type(8))) short bf16x8;
typedef __attribute__((ext_vector_type(4))) float f32x4;

#define HW 16384
#define WPITCH 130   // padded width: col 0 and 129 are zero pads
#define CCAP 192     // candidate cap (count(key>=K*) typically 128..~132)
#define PSTR 28      // patch buffer stride (floats) per (cand, ci)
// workspace byte offsets
#define WSO_XN    0ULL           // bf16 NHWC padded input; LATER pbuf alias
#define WSO_FEATB 34078720ULL    // bf16 NHWC padded feat   (34,078,720)
#define WSO_WP1   68157440ULL    // bf16 [9][256][256] shared_w
#define WSO_WP2   69337088ULL    // bf16 [9][256][256] obj_w1
#define WSO_BNP   70516736ULL    // fp32 scale1,shift1,scale2,shift2,w2f (1280)
#define WSO_LOG   70521856ULL    // fp32 65536 logits
#define WSO_CAND  70784000ULL    // int 4*CCAP
#define WSO_CNT   70787072ULL    // int 4 (+pad)
#define WSO_EXL   70787136ULL    // fp32 4*CCAP
#define WSO_TIDX  70790208ULL    // int 4*100
#define WSO_TLOG  70791808ULL    // fp32 4*100
#define WSO_W1N   70793408ULL    // fp32 [ci][tap][co] shared_w (2,359,296)
#define WSO_W2N   73152704ULL    // fp32 [ci][tap][co] obj_w1   (2,359,296)
#define WSO_PBUF  WSO_XN         // fp32 [b][cand][ci][PSTR] patches (22 MB),
                                 // aliases xn (dead after conv2)

__device__ __forceinline__ float bf2f(short s) {
  return __uint_as_float(((unsigned)(unsigned short)s) << 16);
}
__device__ __forceinline__ short f2bf(float f) {  // RNE
  unsigned u = __float_as_uint(f);
  u += 0x7fffu + ((u >> 16) & 1u);
  return (short)(u >> 16);
}
__device__ __forceinline__ void gll16(const void* g, void* l) {
  __builtin_amdgcn_global_load_lds(
      (const __attribute__((address_space(1))) void*)g,
      (__attribute__((address_space(3))) void*)l, 16, 0, 0);
}

// --- prep: reorder conv weights (co,ci,kh,kw) f32 -> [tap][co][ci] bf16 -----
__global__ void wreorder(const float* __restrict__ src, short* __restrict__ dst) {
  int i = blockIdx.x * 256 + threadIdx.x;  // grid 2304
  int ci = i & 255;
  int r = i >> 8;
  int co = r & 255;
  int tap = r >> 8;
  dst[i] = f2bf(src[(co * 256 + ci) * 9 + tap]);
}

// --- prep: reorder conv weights f32 -> [ci][tap][co] fp32 (for rescore) -----
__global__ void wtrans2(const float* __restrict__ src, float* __restrict__ dst) {
  int i = blockIdx.x * 256 + threadIdx.x;  // grid 2304
  int co = i & 255;
  int r = i >> 8;       // r = ci*9 + k
  int ci = r / 9;
  int k = r % 9;
  dst[i] = src[(co * 256 + ci) * 9 + k];
}

// --- prep: fold BN into scale/shift (fp32-exact), copy w2 -------------------
__global__ void bnprep(const float* g1, const float* b1, const float* m1,
                       const float* v1, const float* g2, const float* b2,
                       const float* m2, const float* v2, const float* w2,
                       float* __restrict__ out) {
  int c = threadIdx.x;
  float s1 = g1[c] / sqrtf(v1[c] + 1e-5f);
  out[c] = s1;
  out[256 + c] = b1[c] - m1[c] * s1;
  float s2 = g2[c] / sqrtf(v2[c] + 1e-5f);
  out[512 + c] = s2;
  out[768 + c] = b2[c] - m2[c] * s2;
  out[1024 + c] = w2[c];
}

// --- zero the W-pad columns of xn and featb ---------------------------------
__global__ void padzero(short* __restrict__ xn, short* __restrict__ featb) {
  int i = blockIdx.x * 256 + threadIdx.x;  // grid 1024 -> 262144
  int c = i & 255;
  int r = i >> 8;            // 0..1023 : nh(512) x side(2)
  int nh = r >> 1;
  int side = r & 1;
  size_t off = ((size_t)nh * WPITCH + (side ? 129 : 0)) * 256 + c;
  xn[off] = 0;
  featb[off] = 0;
}

// --- logits init to 1x1 bias ------------------------------------------------
__global__ void loginit(float* __restrict__ logits, const float* __restrict__ b2) {
  logits[blockIdx.x * 256 + threadIdx.x] = b2[0];
}

// --- NCHW f32 -> NHWC bf16 (padded W) ---------------------------------------
__global__ __launch_bounds__(256) void nchw2nhwc(const float* __restrict__ in,
                                                 short* __restrict__ out) {
  __shared__ short tl[64 * 66];
  int n = blockIdx.z, c0 = blockIdx.y * 64, s0 = blockIdx.x * 64;
  int sl = threadIdx.x & 63, cl = threadIdx.x >> 6;
  for (int p = 0; p < 16; ++p) {
    int c = cl + p * 4;
    tl[c * 66 + sl] = f2bf(in[(((size_t)(n * 256 + c0 + c)) << 14) + s0 + sl]);
  }
  __syncthreads();
  int co = threadIdx.x & 63, so = threadIdx.x >> 6;
  for (int p = 0; p < 16; ++p) {
    int S = s0 + so + p * 4;
    int h = S >> 7, w = S & 127;
    out[(((size_t)(n * 128 + h)) * WPITCH + w + 1) * 256 + c0 + co] =
        tl[co * 66 + (so + p * 4)];
  }
}

// --- 3x3 conv + BN + ReLU via MFMA; OUT_LOGITS fuses the 1x1 score ----------
template <int OUT_LOGITS>
__global__ __launch_bounds__(256) void conv3x3(const short* __restrict__ inp,
                                               const short* __restrict__ wp,
                                               const float* __restrict__ scale,
                                               const float* __restrict__ shift,
                                               const float* __restrict__ w2f,
                                               short* __restrict__ outb,
                                               float* __restrict__ logits) {
  __shared__ short a_sm[128 * 32];
  __shared__ short b_sm[128 * 32];
  const int t = threadIdx.x;
  const int wv = t >> 6, lane = t & 63;
  const int l15 = lane & 15, quad = lane >> 4;
  const int tile = blockIdx.x;
  const int img = tile >> 7;
  const int h = tile & 127;
  const int nblk = blockIdx.y;
  const int m0 = (wv & 1) << 6;
  const int n0 = (wv >> 1) << 6;

  f32x4 acc[4][4];
#pragma unroll
  for (int i = 0; i < 4; ++i)
#pragma unroll
    for (int j = 0; j < 4; ++j) {
      acc[i][j][0] = 0.f; acc[i][j][1] = 0.f;
      acc[i][j][2] = 0.f; acc[i][j][3] = 0.f;
    }

  for (int tap = 0; tap < 9; ++tap) {
    const int dh = tap / 3 - 1, dw = tap % 3 - 1;
    const int hy = h + dh;
    if (hy < 0 || hy > 127) continue;  // block-uniform row-pad skip
    const size_t arow = ((size_t)(img * 128 + hy)) * WPITCH;
    const short* wtap = wp + ((size_t)(tap * 256 + nblk * 128)) * 256;

    for (int c0 = 0; c0 < 256; c0 += 32) {
      __syncthreads();
      // stage A: rows = w (padded cols make all lanes in-bounds: full exec)
#pragma unroll
      for (int j = 0; j < 2; ++j) {
        const int mrow = (j << 6) + (t >> 2);
        const int cc = t & 3;
        gll16(inp + (arow + mrow + dw + 1) * 256 + c0 + cc * 8,
              a_sm + ((size_t)((j << 8) + t)) * 8);
      }
      // stage B: rows = co
#pragma unroll
      for (int j = 0; j < 2; ++j) {
        const int nrow = (j << 6) + (t >> 2);
        const int cc = t & 3;
        gll16(wtap + (size_t)nrow * 256 + c0 + cc * 8,
              b_sm + ((size_t)((j << 8) + t)) * 8);
      }
      __syncthreads();  // vmcnt(0) drain lands the LDS writes

      bf16x8 af[4], bfr[4];
#pragma unroll
      for (int i = 0; i < 4; ++i)
        af[i] = *(const bf16x8*)(a_sm + (m0 + i * 16 + l15) * 32 + quad * 8);
#pragma unroll
      for (int i = 0; i < 4; ++i)
        bfr[i] = *(const bf16x8*)(b_sm + (n0 + i * 16 + l15) * 32 + quad * 8);
#pragma unroll
      for (int i = 0; i < 4; ++i)
#pragma unroll
        for (int j = 0; j < 4; ++j)
          acc[i][j] = __builtin_amdgcn_mfma_f32_16x16x32_bf16(af[i], bfr[j],
                                                              acc[i][j], 0, 0, 0);
    }
  }

  // C/D map: col = lane&15, row = quad*4 + reg
  float sc[4], sh[4], wf[4];
#pragma unroll
  for (int j = 0; j < 4; ++j) {
    const int co = nblk * 128 + n0 + j * 16 + l15;
    sc[j] = scale[co];
    sh[j] = shift[co];
    if (OUT_LOGITS) wf[j] = w2f[co];
  }
  if (OUT_LOGITS) {
    float* lrow = logits + ((size_t)img << 14) + (h << 7);
#pragma unroll
    for (int i = 0; i < 4; ++i) {
#pragma unroll
      for (int r = 0; r < 4; ++r) {
        float part = 0.f;
#pragma unroll
        for (int j = 0; j < 4; ++j) {
          float v = fmaxf(acc[i][j][r] * sc[j] + sh[j], 0.f);
          part += v * wf[j];
        }
        part += __shfl_xor(part, 1);
        part += __shfl_xor(part, 2);
        part += __shfl_xor(part, 4);
        part += __shfl_xor(part, 8);
        if (l15 == 0)
          atomicAdd(&lrow[m0 + i * 16 + quad * 4 + r], part);
      }
    }
  } else {
    const size_t obase = ((size_t)(img * 128 + h)) * WPITCH + 1;
#pragma unroll
    for (int i = 0; i < 4; ++i) {
#pragma unroll
      for (int j = 0; j < 4; ++j) {
        const int co = nblk * 128 + n0 + j * 16 + l15;
#pragma unroll
        for (int r = 0; r < 4; ++r) {
          const int m = m0 + i * 16 + quad * 4 + r;
          float v = fmaxf(acc[i][j][r] * sc[j] + sh[j], 0.f);
          outb[(obase + m) * 256 + co] = f2bf(v);
        }
      }
    }
  }
}

// --- radix-select: all elements with key >= K*, where K* is the exact
// 32-bit key threshold of rank 128. One block per batch. ---------------------
__global__ __launch_bounds__(1024) void topk_radix(const float* __restrict__ logits,
                                                   int* __restrict__ cand,
                                                   int* __restrict__ cnt_out) {
  __shared__ int hist[2048];
  __shared__ int wsum[16];
  __shared__ unsigned sel_bin;
  __shared__ int sel_above;
  __shared__ int cntr;
  const int b = blockIdx.x, t = threadIdx.x;
  const int lane = t & 63, wid = t >> 6;
  const float* L = logits + (size_t)b * HW;
  const int base = t * 16;
  unsigned kv[16];
#pragma unroll
  for (int i = 0; i < 4; ++i) {
    float4 v = *(const float4*)(L + base + i * 4);
    float f4[4] = {v.x, v.y, v.z, v.w};
#pragma unroll
    for (int j = 0; j < 4; ++j) {
      unsigned u = __float_as_uint(f4[j]);
      kv[i * 4 + j] = u ^ (((unsigned)((int)u >> 31)) | 0x80000000u);
    }
  }
  unsigned prefix = 0, pmask = 0;
  int need = 128;
  const int shifts[3] = {21, 10, 0};
  const int nbs[3] = {2048, 2048, 1024};

  for (int lev = 0; lev < 3; ++lev) {
    const int shift = shifts[lev];
    const int nb = nbs[lev];
    hist[t] = 0;
    hist[t + 1024] = 0;
    __syncthreads();
#pragma unroll
    for (int i = 0; i < 16; ++i)
      if ((kv[i] & pmask) == prefix)
        atomicAdd(&hist[(kv[i] >> shift) & (nb - 1)], 1);
    __syncthreads();
    // descending chunk ownership: thread t owns bins [bin_hi-cs+1 .. bin_hi]
    const int cs = nb >> 10;  // 2 or 1
    const int bin_hi = nb - 1 - t * cs;
    const int c_hi = hist[bin_hi];
    const int c_lo = (cs == 2) ? hist[bin_hi - 1] : 0;
    const int s = c_hi + c_lo;
    // exclusive scan over thread order
    int inc = s;
    for (int off = 1; off < 64; off <<= 1) {
      int nbr = __shfl_up(inc, off);
      if (lane >= off) inc += nbr;
    }
    if (lane == 63) wsum[wid] = inc;
    __syncthreads();
    if (wid == 0) {
      int wv = (lane < 16) ? wsum[lane] : 0;
      for (int off = 1; off < 16; off <<= 1) {
        int nbr = __shfl_up(wv, off);
        if (lane >= off) wv += nbr;
      }
      if (lane < 16) wsum[lane] = wv;
    }
    __syncthreads();
    const int excl = inc - s + (wid ? wsum[wid - 1] : 0);
    if (excl < need && need <= excl + s) {  // exactly one thread
      if (need <= excl + c_hi) {
        sel_bin = (unsigned)bin_hi;
        sel_above = excl;
      } else {
        sel_bin = (unsigned)(bin_hi - 1);
        sel_above = excl + c_hi;
      }
    }
    __syncthreads();
    prefix |= sel_bin << shift;
    pmask |= ((unsigned)(nb - 1)) << shift;
    need -= sel_above;
    __syncthreads();
  }
  // prefix == K* (exact rank-128 key). Select key >= K* (>=128 elems).
  if (t == 0) cntr = 0;
  __syncthreads();
#pragma unroll
  for (int i = 0; i < 16; ++i) {
    if (kv[i] >= prefix) {
      int p = atomicAdd(&cntr, 1);
      if (p < CCAP) cand[b * CCAP + p] = base + i;
    }
  }
  __syncthreads();
  if (t == 0) cnt_out[b] = (cntr < CCAP) ? cntr : CCAP;
}

// --- stage zero-padded 5x5x256 patches to global ----------------------------
// pbuf[((b*CCAP + c)*256 + ci)*PSTR + p], p = r*5 + j.
// Lane map: e = t + 256k -> (ci = e/25, r = (e%25)/5, j fastest) so lanes
// 0..4 read 5 CONSECUTIVE floats per (ci,row) => ~13 line-touches/inst vs 64.
__global__ __launch_bounds__(256) void patchstage(const float* __restrict__ x,
                                                  const int* __restrict__ cand,
                                                  const int* __restrict__ cnt,
                                                  float* __restrict__ pbuf) {
  const int c = blockIdx.x, b = blockIdx.y, t = threadIdx.x;
  if (c >= cnt[b]) return;
  const int s = cand[b * CCAP + c];
  const int h0 = (s >> 7) - 2, w0 = (s & 127) - 2;
  const float* xb = x + ((size_t)b << 22);
  float* pc = pbuf + (size_t)(b * CCAP + c) * (256 * PSTR);
#pragma unroll
  for (int k = 0; k < 25; ++k) {
    int e = t + (k << 8);
    int ci = e / 25;
    int rj = e - ci * 25;
    int r = rj / 5;
    int j = rj - r * 5;
    int hy = h0 + r, wx = w0 + j;
    float v = 0.f;
    if (hy >= 0 && hy < 128 && wx >= 0 && wx < 128)
      v = xb[((size_t)ci << 14) + (hy << 7) + wx];
    pc[ci * PSTR + rj] = v;
  }
}

// --- EXACT fp32 rescore: 1024 threads, 4-way split-K over ci ----------------
// thread = (co = t&255, ks = readfirstlane(t>>8)); each wave covers 64 ci.
// Patches via scalar pipe (wave-uniform pbuf pointers); weights [ci][tap][co]
// coalesced. Partials combined in LDS.
__global__ __launch_bounds__(1024) void rescore(const float* __restrict__ pbuf,
                                                const float* __restrict__ w1n,
                                                const float* __restrict__ w2n,
                                                const float* __restrict__ bnp,
                                                const float* __restrict__ b2,
                                                const int* __restrict__ cand,
                                                const int* __restrict__ cnt,
                                                float* __restrict__ exlog) {
  const int c = blockIdx.x, b = blockIdx.y;
  if (c >= cnt[b]) return;  // block-uniform early exit
  const int t = threadIdx.x;
  const int co = t & 255;
  const int ks = __builtin_amdgcn_readfirstlane(t >> 8);  // wave-uniform
  __shared__ float a1p[256 * 4 * 9];  // conv1 partials [co][ks][p] (36 KB)
  __shared__ float f9_sm[256 * 12];   // combined feats [ci][12]     (12 KB)
  __shared__ float accp[256 * 4];     // conv2 partials [co][ks]     (4 KB)
  __shared__ float red[4];
  const float* pp = pbuf + ((size_t)(b * CCAP + c)) * (256 * PSTR);
  const int ci0 = ks << 6;

  // conv1 partial over this wave's 64 ci
  float a9[9];
#pragma unroll
  for (int p = 0; p < 9; ++p) a9[p] = 0.f;
  for (int ci = ci0; ci < ci0 + 64; ++ci) {
    const float* pc = pp + ci * PSTR;  // wave-uniform -> s_load
    float xp[25];
#pragma unroll
    for (int p = 0; p < 25; ++p) xp[p] = pc[p];
    const float* wr = w1n + (size_t)ci * 2304 + co;
    float w9[9];
#pragma unroll
    for (int k = 0; k < 9; ++k) w9[k] = wr[k * 256];
#pragma unroll
    for (int py = 0; py < 3; ++py)
#pragma unroll
      for (int px = 0; px < 3; ++px)
#pragma unroll
        for (int ky = 0; ky < 3; ++ky)
#pragma unroll
          for (int kx = 0; kx < 3; ++kx)
            a9[py * 3 + px] += w9[ky * 3 + kx] * xp[(py + ky) * 5 + px + kx];
  }
#pragma unroll
  for (int p = 0; p < 9; ++p) a1p[(co * 4 + ks) * 9 + p] = a9[p];
  __syncthreads();

  // combine + BN + ReLU (first 4 waves)
  if (t < 256) {
    const float sc1 = bnp[t], sh1 = bnp[256 + t];
#pragma unroll
    for (int p = 0; p < 9; ++p) {
      float v = a1p[t * 36 + p] + a1p[t * 36 + 9 + p] +
                a1p[t * 36 + 18 + p] + a1p[t * 36 + 27 + p];
      f9_sm[t * 12 + p] = fmaxf(v * sc1 + sh1, 0.f);
    }
  }
  __syncthreads();

  // conv2 partial over this wave's 64 ci (f9 via broadcast b128 reads)
  float acc = 0.f;
  for (int ci = ci0; ci < ci0 + 64; ++ci) {
    float f9[12];
    const float4* fr = (const float4*)(f9_sm + ci * 12);
#pragma unroll
    for (int q = 0; q < 3; ++q) {
      float4 v = fr[q];
      f9[q * 4 + 0] = v.x; f9[q * 4 + 1] = v.y;
      f9[q * 4 + 2] = v.z; f9[q * 4 + 3] = v.w;
    }
    const float* wr = w2n + (size_t)ci * 2304 + co;
#pragma unroll
    for (int k = 0; k < 9; ++k) acc += wr[k * 256] * f9[k];
  }
  accp[co * 4 + ks] = acc;
  __syncthreads();

  if (t < 256) {
    float a = accp[t * 4] + accp[t * 4 + 1] + accp[t * 4 + 2] + accp[t * 4 + 3];
    const float hv = fmaxf(a * bnp[512 + t] + bnp[768 + t], 0.f);
    float p = hv * bnp[1024 + t];
    for (int off = 32; off; off >>= 1) p += __shfl_xor(p, off);
    if ((t & 63) == 0) red[t >> 6] = p;
  }
  __syncthreads();
  if (t == 0) exlog[b * CCAP + c] = red[0] + red[1] + red[2] + red[3] + b2[0];
}

// --- rank-sort exact logits, keep top-100 (jax tie-break: lower idx) --------
__global__ __launch_bounds__(CCAP) void final_topk(const float* __restrict__ exlog,
                                                   const int* __restrict__ cand,
                                                   const int* __restrict__ cnt,
                                                   int* __restrict__ tidx,
                                                   float* __restrict__ tlog) {
  const int b = blockIdx.x, t = threadIdx.x;
  __shared__ float v[CCAP];
  __shared__ int si[CCAP];
  const int n = cnt[b];
  float mv = (t < n) ? exlog[b * CCAP + t] : -3.0e38f;
  int s = (t < n) ? cand[b * CCAP + t] : 0x7FFFFFFF;
  v[t] = mv;
  si[t] = s;
  __syncthreads();
  int rank = 0;
  for (int j = 0; j < CCAP; ++j) {
    float vj = v[j];
    int sj = si[j];
    if (vj > mv || (vj == mv && sj < s)) ++rank;
  }
  if (t < n && rank < 100) {
    tidx[b * 100 + rank] = s;
    tlog[b * 100 + rank] = mv;
  }
}

// --- fused FFN + LN + heads + anchor (fp32 out), one block per query --------
__global__ __launch_bounds__(256) void head_kern(
    const short* __restrict__ featb, const int* __restrict__ tidx,
    const float* __restrict__ tlog, const float* __restrict__ tmpl,
    const float* __restrict__ w1, const float* __restrict__ b1,
    const float* __restrict__ lng, const float* __restrict__ lnb,
    const float* __restrict__ w2, const float* __restrict__ b2,
    const float* __restrict__ zw, const float* __restrict__ zb,
    const float* __restrict__ dmw, const float* __restrict__ dmb,
    const float* __restrict__ yw, const float* __restrict__ yb,
    const float* __restrict__ vw, const float* __restrict__ vb,
    float* __restrict__ out) {
  const int blk = blockIdx.x;  // 400
  const int b = blk / 100, q = blk % 100;
  const int t = threadIdx.x;
  const int lane = t & 63, wid = t >> 6;
  __shared__ float g[256];
  __shared__ float sx[256];
  __shared__ float red[4];
  __shared__ float heads[8];

  const int s = tidx[b * 100 + q];
  const float score = 1.f / (1.f + expf(-tlog[b * 100 + q]));
  const int ys = s >> 7, xs = s & 127;

  g[t] = bf2f(featb[(((size_t)(b * 128 + ys)) * WPITCH + xs + 1) * 256 + t]);
  __syncthreads();

  float x = b1[t];
  {
    const float* wr = w1 + (size_t)t * 256;
    for (int i = 0; i < 256; i += 4) {
      float4 wv = *(const float4*)(wr + i);
      x += g[i] * wv.x + g[i + 1] * wv.y + g[i + 2] * wv.z + g[i + 3] * wv.w;
    }
  }
  float sum = x;
  for (int off = 32; off; off >>= 1) sum += __shfl_xor(sum, off);
  if (lane == 0) red[wid] = sum;
  __syncthreads();
  float mu = (red[0] + red[1] + red[2] + red[3]) * (1.f / 256.f);
  __syncthreads();
  float d = x - mu;
  float q2 = d * d;
  for (int off = 32; off; off >>= 1) q2 += __shfl_xor(q2, off);
  if (lane == 0) red[wid] = q2;
  __syncthreads();
  float var = (red[0] + red[1] + red[2] + red[3]) * (1.f / 256.f);
  float xn = d * (1.f / sqrtf(var + 1e-5f)) * lng[t] + lnb[t];
  xn = fmaxf(xn, 0.f);
  sx[t] = xn;
  __syncthreads();
  float pf = b2[t];
  {
    const float* wr = w2 + (size_t)t * 256;
    for (int i = 0; i < 256; i += 4) {
      float4 wv = *(const float4*)(wr + i);
      pf += sx[i] * wv.x + sx[i + 1] * wv.y + sx[i + 2] * wv.z + sx[i + 3] * wv.w;
    }
  }
  pf *= (1.f + score);
  out[(size_t)(b * 100 + q) * 256 + t] = pf;

  const int k = t >> 5, l = t & 31;
  const float* hw;
  float hb;
  if (k == 0)      { hw = zw;                 hb = zb[0]; }
  else if (k < 4)  { hw = dmw + (k - 1) * 256; hb = dmb[k - 1]; }
  else if (k < 6)  { hw = yw + (k - 4) * 256;  hb = yb[k - 4]; }
  else             { hw = vw + (k - 6) * 256;  hb = vb[k - 6]; }
  float hp = 0.f;
#pragma unroll
  for (int r = 0; r < 8; ++r) {
    int i = l + r * 32;
    hp += g[i] * hw[i];
  }
  for (int off = 16; off; off >>= 1) hp += __shfl_xor(hp, off);
  if (l == 0) heads[k] = hp + hb;
  __syncthreads();

  if (t == 0) {
    const float* pa = tmpl + ((size_t)b * 900 + q) * 11;
    float p[11];
#pragma unroll
    for (int i = 0; i < 11; ++i) p[i] = pa[i];
    float a[11];
    a[0] = ((float)xs + 0.5f) * 0.8f - 51.2f;
    a[1] = ((float)ys + 0.5f) * 0.8f - 51.2f;
    a[2] = p[2] + 0.5f * heads[0];
#pragma unroll
    for (int i = 0; i < 3; ++i)
      a[3 + i] = p[3 + i] + 0.2f * fminf(fmaxf(heads[1 + i], -1.f), 1.f);
    float t0 = tanhf(heads[4]), t1 = tanhf(heads[5]);
    float nrm = fmaxf(sqrtf(t0 * t0 + t1 * t1), 1e-6f);
    a[6] = 0.7f * p[6] + 0.3f * t0 / nrm;
    a[7] = 0.7f * p[7] + 0.3f * t1 / nrm;
    a[8] = p[8] + 0.2f * fminf(fmaxf(heads[6], -2.f), 2.f);
    a[9] = p[9] + 0.2f * fminf(fmaxf(heads[7], -2.f), 2.f);
    a[10] = p[10];
    float* oa = out + 102400 + (size_t)(b * 100 + q) * 11;
#pragma unroll
    for (int i = 0; i < 11; ++i) oa[i] = a[i];
    out[106800 + b * 100 + q] = score;
  }
}

extern "C" void kernel_launch(void* const* d_in, const int* in_sizes, int n_in,
                              void* d_out, int out_size, void* d_ws, size_t ws_size,
                              hipStream_t stream) {
  (void)in_sizes; (void)n_in; (void)out_size; (void)ws_size;
  char* ws = (char*)d_ws;
  short* xn     = (short*)(ws + WSO_XN);
  short* featb  = (short*)(ws + WSO_FEATB);
  short* wp1    = (short*)(ws + WSO_WP1);
  short* wp2    = (short*)(ws + WSO_WP2);
  float* bnp    = (float*)(ws + WSO_BNP);
  float* logits = (float*)(ws + WSO_LOG);
  int*   cand   = (int*)(ws + WSO_CAND);
  int*   cnt    = (int*)(ws + WSO_CNT);
  float* exl    = (float*)(ws + WSO_EXL);
  int*   tidx   = (int*)(ws + WSO_TIDX);
  float* tlog   = (float*)(ws + WSO_TLOG);
  float* w1n    = (float*)(ws + WSO_W1N);
  float* w2n    = (float*)(ws + WSO_W2N);
  float* pbuf   = (float*)(ws + WSO_PBUF);  // aliases xn (dead after conv2)

  const float* bev = (const float*)d_in[0];

  wreorder<<<2304, 256, 0, stream>>>((const float*)d_in[2], wp1);
  wreorder<<<2304, 256, 0, stream>>>((const float*)d_in[7], wp2);
  wtrans2<<<2304, 256, 0, stream>>>((const float*)d_in[2], w1n);
  wtrans2<<<2304, 256, 0, stream>>>((const float*)d_in[7], w2n);
  bnprep<<<1, 256, 0, stream>>>(
      (const float*)d_in[3], (const float*)d_in[4], (const float*)d_in[5],
      (const float*)d_in[6], (const float*)d_in[8], (const float*)d_in[9],
      (const float*)d_in[10], (const float*)d_in[11], (const float*)d_in[12], bnp);
  padzero<<<1024, 256, 0, stream>>>(xn, featb);
  loginit<<<256, 256, 0, stream>>>(logits, (const float*)d_in[13]);
  nchw2nhwc<<<dim3(256, 4, 4), 256, 0, stream>>>(bev, xn);
  conv3x3<0><<<dim3(512, 2), 256, 0, stream>>>(xn, wp1, bnp, bnp + 256,
                                               nullptr, featb, nullptr);
  conv3x3<1><<<dim3(512, 2), 256, 0, stream>>>(featb, wp2, bnp + 512, bnp + 768,
                                               bnp + 1024, nullptr, logits);
  topk_radix<<<4, 1024, 0, stream>>>(logits, cand, cnt);
  // xn is dead from here on; pbuf reuses its storage.
  patchstage<<<dim3(CCAP, 4), 256, 0, stream>>>(bev, cand, cnt, pbuf);
  rescore<<<dim3(CCAP, 4), 1024, 0, stream>>>(pbuf, w1n, w2n, bnp,
                                              (const float*)d_in[13], cand, cnt,
                                              exl);
  final_topk<<<4, CCAP, 0, stream>>>(exl, cand, cnt, tidx, tlog);
  head_kern<<<400, 256, 0, stream>>>(
      featb, tidx, tlog, (const float*)d_in[1],
      (const float*)d_in[14], (const float*)d_in[15], (const float*)d_in[16],
      (const float*)d_in[17], (const float*)d_in[18], (const float*)d_in[19],
      (const float*)d_in[20], (const float*)d_in[21], (const float*)d_in[22],
      (const float*)d_in[23], (const float*)d_in[24], (const float*)d_in[25],
      (const float*)d_in[26], (const float*)d_in[27], (float*)d_out);
}

// Round 8
// 546.044 us; speedup vs baseline: 1.3412x; 1.1688x over previous
//
#include <hip/hip_runtime.h>
#include <math.h>

// ---------------------------------------------------------------------------
// LiDARPriorQueryGenerator — MI355X (gfx950). FP32 I/O per reference dtypes.
// wprep(bf16 [tap][co][ci] + fp32 [ci][tap][co], bn-fold) -> NHWC bf16
// (W padded 130) -> conv1 MFMA (dh-merged barrier windows) -> featb bf16 ->
// conv2 MFMA + fused 1x1 score -> RADIX-SELECT top>=128 -> patchstage ->
// EXACT fp32 rescore (G=2 pairs, 1024 thr, 4-way split-K, scalar patches)
// -> final top-100 -> fused FFN/LN/heads/anchor.
// ---------------------------------------------------------------------------

typedef __attribute__((ext_vector_type(8))) short bf16x8;
typedef __attribute__((ext_vector_type(4))) float f32x4;

#define HW 16384
#define WPITCH 130   // padded width: col 0 and 129 are zero pads
#define CCAP 192     // candidate cap (count(key>=K*) typically 128..~132)
#define PSTR 28      // patch buffer stride (floats) per (cand, ci)
// workspace byte offsets
#define WSO_XN    0ULL           // bf16 NHWC padded input; LATER pbuf alias
#define WSO_FEATB 34078720ULL    // bf16 NHWC padded feat   (34,078,720)
#define WSO_WP1   68157440ULL    // bf16 [9][256][256] shared_w
#define WSO_WP2   69337088ULL    // bf16 [9][256][256] obj_w1
#define WSO_BNP   70516736ULL    // fp32 scale1,shift1,scale2,shift2,w2f (1280)
#define WSO_LOG   70521856ULL    // fp32 65536 logits
#define WSO_CAND  70784000ULL    // int 4*CCAP
#define WSO_CNT   70787072ULL    // int 4 (+pad)
#define WSO_EXL   70787136ULL    // fp32 4*CCAP
#define WSO_TIDX  70790208ULL    // int 4*100
#define WSO_TLOG  70791808ULL    // fp32 4*100
#define WSO_W1N   70793408ULL    // fp32 [ci][tap][co] shared_w (2,359,296)
#define WSO_W2N   73152704ULL    // fp32 [ci][tap][co] obj_w1   (2,359,296)
#define WSO_PBUF  WSO_XN         // fp32 [b][cand][ci][PSTR] patches (22 MB)

__device__ __forceinline__ float bf2f(short s) {
  return __uint_as_float(((unsigned)(unsigned short)s) << 16);
}
__device__ __forceinline__ short f2bf(float f) {  // RNE
  unsigned u = __float_as_uint(f);
  u += 0x7fffu + ((u >> 16) & 1u);
  return (short)(u >> 16);
}
__device__ __forceinline__ void gll16(const void* g, void* l) {
  __builtin_amdgcn_global_load_lds(
      (const __attribute__((address_space(1))) void*)g,
      (__attribute__((address_space(3))) void*)l, 16, 0, 0);
}

// --- prep: one coalesced read of (co,ci,kh,kw) weights, two scattered writes:
//   wp  bf16 [tap][co][ci]  (for MFMA conv)
//   wn  fp32 [ci][tap][co]  (for exact rescore)
__global__ void wprep(const float* __restrict__ src, short* __restrict__ wp,
                      float* __restrict__ wn) {
  int i = blockIdx.x * 256 + threadIdx.x;  // grid 2304 -> 589824, coalesced
  float v = src[i];
  int k = i % 9;
  int r = i / 9;
  int ci = r & 255;
  int co = r >> 8;
  wp[(k * 256 + co) * 256 + ci] = f2bf(v);
  wn[(ci * 9 + k) * 256 + co] = v;
}

// --- prep: fold BN into scale/shift (fp32-exact), copy w2 -------------------
__global__ void bnprep(const float* g1, const float* b1, const float* m1,
                       const float* v1, const float* g2, const float* b2,
                       const float* m2, const float* v2, const float* w2,
                       float* __restrict__ out) {
  int c = threadIdx.x;
  float s1 = g1[c] / sqrtf(v1[c] + 1e-5f);
  out[c] = s1;
  out[256 + c] = b1[c] - m1[c] * s1;
  float s2 = g2[c] / sqrtf(v2[c] + 1e-5f);
  out[512 + c] = s2;
  out[768 + c] = b2[c] - m2[c] * s2;
  out[1024 + c] = w2[c];
}

// --- zero the W-pad columns of xn and featb ---------------------------------
__global__ void padzero(short* __restrict__ xn, short* __restrict__ featb) {
  int i = blockIdx.x * 256 + threadIdx.x;  // grid 1024 -> 262144
  int c = i & 255;
  int r = i >> 8;
  int nh = r >> 1;
  int side = r & 1;
  size_t off = ((size_t)nh * WPITCH + (side ? 129 : 0)) * 256 + c;
  xn[off] = 0;
  featb[off] = 0;
}

// --- logits init to 1x1 bias ------------------------------------------------
__global__ void loginit(float* __restrict__ logits, const float* __restrict__ b2) {
  logits[blockIdx.x * 256 + threadIdx.x] = b2[0];
}

// --- NCHW f32 -> NHWC bf16 (padded W) ---------------------------------------
__global__ __launch_bounds__(256) void nchw2nhwc(const float* __restrict__ in,
                                                 short* __restrict__ out) {
  __shared__ short tl[64 * 66];
  int n = blockIdx.z, c0 = blockIdx.y * 64, s0 = blockIdx.x * 64;
  int sl = threadIdx.x & 63, cl = threadIdx.x >> 6;
  for (int p = 0; p < 16; ++p) {
    int c = cl + p * 4;
    tl[c * 66 + sl] = f2bf(in[(((size_t)(n * 256 + c0 + c)) << 14) + s0 + sl]);
  }
  __syncthreads();
  int co = threadIdx.x & 63, so = threadIdx.x >> 6;
  for (int p = 0; p < 16; ++p) {
    int S = s0 + so + p * 4;
    int h = S >> 7, w = S & 127;
    out[(((size_t)(n * 128 + h)) * WPITCH + w + 1) * 256 + c0 + co] =
        tl[co * 66 + (so + p * 4)];
  }
}

// --- 3x3 conv + BN + ReLU via MFMA; dh-merged staging: one barrier window
// per (dh, c0) covers 3 dw shifts of A and 3 taps of B -> 48 MFMA per drain.
template <int OUT_LOGITS>
__global__ __launch_bounds__(256) void conv3x3(const short* __restrict__ inp,
                                               const short* __restrict__ wp,
                                               const float* __restrict__ scale,
                                               const float* __restrict__ shift,
                                               const float* __restrict__ w2f,
                                               short* __restrict__ outb,
                                               float* __restrict__ logits) {
  __shared__ short a_sm[3][128 * 32];
  __shared__ short b_sm[3][128 * 32];
  const int t = threadIdx.x;
  const int wv = t >> 6, lane = t & 63;
  const int l15 = lane & 15, quad = lane >> 4;
  const int tile = blockIdx.x;
  const int img = tile >> 7;
  const int h = tile & 127;
  const int nblk = blockIdx.y;
  const int m0 = (wv & 1) << 6;
  const int n0 = (wv >> 1) << 6;

  f32x4 acc[4][4];
#pragma unroll
  for (int i = 0; i < 4; ++i)
#pragma unroll
    for (int j = 0; j < 4; ++j) {
      acc[i][j][0] = 0.f; acc[i][j][1] = 0.f;
      acc[i][j][2] = 0.f; acc[i][j][3] = 0.f;
    }

  for (int dhi = 0; dhi < 3; ++dhi) {
    const int hy = h + dhi - 1;
    if (hy < 0 || hy > 127) continue;  // block-uniform row-pad skip
    const size_t arow = ((size_t)(img * 128 + hy)) * WPITCH;
    const short* wbase = wp + ((size_t)(dhi * 3 * 256 + nblk * 128)) * 256;

    for (int c0 = 0; c0 < 256; c0 += 32) {
      __syncthreads();
      // stage A: 3 dw-shifted 128x32 tiles (pad cols keep full exec)
#pragma unroll
      for (int dwi = 0; dwi < 3; ++dwi) {
#pragma unroll
        for (int j = 0; j < 2; ++j) {
          const int mrow = (j << 6) + (t >> 2);
          const int cc = t & 3;
          gll16(inp + (arow + mrow + dwi) * 256 + c0 + cc * 8,
                a_sm[dwi] + ((size_t)((j << 8) + t)) * 8);
        }
      }
      // stage B: 3 taps of this dh row
#pragma unroll
      for (int dwi = 0; dwi < 3; ++dwi) {
        const short* wtap = wbase + (size_t)dwi * 65536;
#pragma unroll
        for (int j = 0; j < 2; ++j) {
          const int nrow = (j << 6) + (t >> 2);
          const int cc = t & 3;
          gll16(wtap + (size_t)nrow * 256 + c0 + cc * 8,
                b_sm[dwi] + ((size_t)((j << 8) + t)) * 8);
        }
      }
      __syncthreads();  // single drain for 12 gll16 -> 48 MFMA

#pragma unroll
      for (int dwi = 0; dwi < 3; ++dwi) {
        bf16x8 af[4], bfr[4];
#pragma unroll
        for (int i = 0; i < 4; ++i)
          af[i] = *(const bf16x8*)(a_sm[dwi] + (m0 + i * 16 + l15) * 32 + quad * 8);
#pragma unroll
        for (int i = 0; i < 4; ++i)
          bfr[i] = *(const bf16x8*)(b_sm[dwi] + (n0 + i * 16 + l15) * 32 + quad * 8);
#pragma unroll
        for (int i = 0; i < 4; ++i)
#pragma unroll
          for (int j = 0; j < 4; ++j)
            acc[i][j] = __builtin_amdgcn_mfma_f32_16x16x32_bf16(af[i], bfr[j],
                                                                acc[i][j], 0, 0, 0);
      }
    }
  }

  // C/D map: col = lane&15, row = quad*4 + reg
  float sc[4], sh[4], wf[4];
#pragma unroll
  for (int j = 0; j < 4; ++j) {
    const int co = nblk * 128 + n0 + j * 16 + l15;
    sc[j] = scale[co];
    sh[j] = shift[co];
    if (OUT_LOGITS) wf[j] = w2f[co];
  }
  if (OUT_LOGITS) {
    float* lrow = logits + ((size_t)img << 14) + (h << 7);
#pragma unroll
    for (int i = 0; i < 4; ++i) {
#pragma unroll
      for (int r = 0; r < 4; ++r) {
        float part = 0.f;
#pragma unroll
        for (int j = 0; j < 4; ++j) {
          float v = fmaxf(acc[i][j][r] * sc[j] + sh[j], 0.f);
          part += v * wf[j];
        }
        part += __shfl_xor(part, 1);
        part += __shfl_xor(part, 2);
        part += __shfl_xor(part, 4);
        part += __shfl_xor(part, 8);
        if (l15 == 0)
          atomicAdd(&lrow[m0 + i * 16 + quad * 4 + r], part);
      }
    }
  } else {
    const size_t obase = ((size_t)(img * 128 + h)) * WPITCH + 1;
#pragma unroll
    for (int i = 0; i < 4; ++i) {
#pragma unroll
      for (int j = 0; j < 4; ++j) {
        const int co = nblk * 128 + n0 + j * 16 + l15;
#pragma unroll
        for (int r = 0; r < 4; ++r) {
          const int m = m0 + i * 16 + quad * 4 + r;
          float v = fmaxf(acc[i][j][r] * sc[j] + sh[j], 0.f);
          outb[(obase + m) * 256 + co] = f2bf(v);
        }
      }
    }
  }
}

// --- radix-select: all elements with key >= K* (exact rank-128 key) ---------
__global__ __launch_bounds__(1024) void topk_radix(const float* __restrict__ logits,
                                                   int* __restrict__ cand,
                                                   int* __restrict__ cnt_out) {
  __shared__ int hist[2048];
  __shared__ int wsum[16];
  __shared__ unsigned sel_bin;
  __shared__ int sel_above;
  __shared__ int cntr;
  const int b = blockIdx.x, t = threadIdx.x;
  const int lane = t & 63, wid = t >> 6;
  const float* L = logits + (size_t)b * HW;
  const int base = t * 16;
  unsigned kv[16];
#pragma unroll
  for (int i = 0; i < 4; ++i) {
    float4 v = *(const float4*)(L + base + i * 4);
    float f4[4] = {v.x, v.y, v.z, v.w};
#pragma unroll
    for (int j = 0; j < 4; ++j) {
      unsigned u = __float_as_uint(f4[j]);
      kv[i * 4 + j] = u ^ (((unsigned)((int)u >> 31)) | 0x80000000u);
    }
  }
  unsigned prefix = 0, pmask = 0;
  int need = 128;
  const int shifts[3] = {21, 10, 0};
  const int nbs[3] = {2048, 2048, 1024};

  for (int lev = 0; lev < 3; ++lev) {
    const int shift = shifts[lev];
    const int nb = nbs[lev];
    hist[t] = 0;
    hist[t + 1024] = 0;
    __syncthreads();
#pragma unroll
    for (int i = 0; i < 16; ++i)
      if ((kv[i] & pmask) == prefix)
        atomicAdd(&hist[(kv[i] >> shift) & (nb - 1)], 1);
    __syncthreads();
    const int cs = nb >> 10;
    const int bin_hi = nb - 1 - t * cs;
    const int c_hi = hist[bin_hi];
    const int c_lo = (cs == 2) ? hist[bin_hi - 1] : 0;
    const int s = c_hi + c_lo;
    int inc = s;
    for (int off = 1; off < 64; off <<= 1) {
      int nbr = __shfl_up(inc, off);
      if (lane >= off) inc += nbr;
    }
    if (lane == 63) wsum[wid] = inc;
    __syncthreads();
    if (wid == 0) {
      int wv = (lane < 16) ? wsum[lane] : 0;
      for (int off = 1; off < 16; off <<= 1) {
        int nbr = __shfl_up(wv, off);
        if (lane >= off) wv += nbr;
      }
      if (lane < 16) wsum[lane] = wv;
    }
    __syncthreads();
    const int excl = inc - s + (wid ? wsum[wid - 1] : 0);
    if (excl < need && need <= excl + s) {
      if (need <= excl + c_hi) {
        sel_bin = (unsigned)bin_hi;
        sel_above = excl;
      } else {
        sel_bin = (unsigned)(bin_hi - 1);
        sel_above = excl + c_hi;
      }
    }
    __syncthreads();
    prefix |= sel_bin << shift;
    pmask |= ((unsigned)(nb - 1)) << shift;
    need -= sel_above;
    __syncthreads();
  }
  if (t == 0) cntr = 0;
  __syncthreads();
#pragma unroll
  for (int i = 0; i < 16; ++i) {
    if (kv[i] >= prefix) {
      int p = atomicAdd(&cntr, 1);
      if (p < CCAP) cand[b * CCAP + p] = base + i;
    }
  }
  __syncthreads();
  if (t == 0) cnt_out[b] = (cntr < CCAP) ? cntr : CCAP;
}

// --- stage zero-padded 5x5x256 patches to global ----------------------------
__global__ __launch_bounds__(256) void patchstage(const float* __restrict__ x,
                                                  const int* __restrict__ cand,
                                                  const int* __restrict__ cnt,
                                                  float* __restrict__ pbuf) {
  const int c = blockIdx.x, b = blockIdx.y, t = threadIdx.x;
  if (c >= cnt[b]) return;
  const int s = cand[b * CCAP + c];
  const int h0 = (s >> 7) - 2, w0 = (s & 127) - 2;
  const float* xb = x + ((size_t)b << 22);
  float* pc = pbuf + (size_t)(b * CCAP + c) * (256 * PSTR);
#pragma unroll
  for (int k = 0; k < 25; ++k) {
    int e = t + (k << 8);
    int ci = e / 25;
    int rj = e - ci * 25;
    int r = rj / 5;
    int j = rj - r * 5;
    int hy = h0 + r, wx = w0 + j;
    float v = 0.f;
    if (hy >= 0 && hy < 128 && wx >= 0 && wx < 128)
      v = xb[((size_t)ci << 14) + (hy << 7) + wx];
    pc[ci * PSTR + rj] = v;
  }
}

// --- EXACT fp32 rescore: G=2 candidate pairs, 1024 thr, 4-way split-K -------
// Grid is EXACTLY 256 blocks (dim3(64,4)): block bx does pair (bx, bx+64)
// [always valid: cnt>=128], then a rare G=1 pass for c=bx+128<cnt.
// One weight read feeds both candidates -> L2 weight traffic halved.
__global__ __launch_bounds__(1024) void rescore(const float* __restrict__ pbuf,
                                                const float* __restrict__ w1n,
                                                const float* __restrict__ w2n,
                                                const float* __restrict__ bnp,
                                                const float* __restrict__ b2,
                                                const int* __restrict__ cand,
                                                const int* __restrict__ cnt,
                                                float* __restrict__ exlog) {
  const int bx = blockIdx.x, b = blockIdx.y, t = threadIdx.x;
  const int n = cnt[b];
  const int co = t & 255;
  const int ks = __builtin_amdgcn_readfirstlane(t >> 8);  // wave-uniform
  const int ci0 = ks << 6;
  __shared__ float a1pA[4 * 256 * 9];  // conv1 partials [ks][co][p] (36 KB)
  __shared__ float a1pB[4 * 256 * 9];
  __shared__ float f9A[256 * 12];      // feats [ci][12] (12 KB)
  __shared__ float f9B[256 * 12];
  __shared__ float accA_p[4 * 256];    // conv2 partials [ks][co] (4 KB)
  __shared__ float accB_p[4 * 256];
  __shared__ float redA[4], redB[4];

  for (int pass = 0; pass < 2; ++pass) {
    const int c0 = bx + (pass ? 128 : 0);
    if (c0 >= n) break;  // block-uniform (pass 0 never breaks: n >= 128)
    const int c1 = bx + 64;
    const bool hasB = (pass == 0);
    if (pass) __syncthreads();  // protect LDS reuse across passes

    const float* ppA = pbuf + ((size_t)(b * CCAP + c0)) * (256 * PSTR);
    const float* ppB = pbuf + ((size_t)(b * CCAP + (hasB ? c1 : c0))) * (256 * PSTR);

    // conv1 partial over this wave's 64 ci, both candidates per weight read
    float aA[9], aB[9];
#pragma unroll
    for (int p = 0; p < 9; ++p) { aA[p] = 0.f; aB[p] = 0.f; }
    for (int ci = ci0; ci < ci0 + 64; ++ci) {
      const float* wr = w1n + (size_t)ci * 2304 + co;
      float w9[9];
#pragma unroll
      for (int k = 0; k < 9; ++k) w9[k] = wr[k * 256];
      {
        const float* pc = ppA + ci * PSTR;  // wave-uniform -> scalar loads
        float xp[25];
#pragma unroll
        for (int p = 0; p < 25; ++p) xp[p] = pc[p];
#pragma unroll
        for (int py = 0; py < 3; ++py)
#pragma unroll
          for (int px = 0; px < 3; ++px)
#pragma unroll
            for (int ky = 0; ky < 3; ++ky)
#pragma unroll
              for (int kx = 0; kx < 3; ++kx)
                aA[py * 3 + px] += w9[ky * 3 + kx] * xp[(py + ky) * 5 + px + kx];
      }
      if (hasB) {
        const float* pc = ppB + ci * PSTR;
        float xp[25];
#pragma unroll
        for (int p = 0; p < 25; ++p) xp[p] = pc[p];
#pragma unroll
        for (int py = 0; py < 3; ++py)
#pragma unroll
          for (int px = 0; px < 3; ++px)
#pragma unroll
            for (int ky = 0; ky < 3; ++ky)
#pragma unroll
              for (int kx = 0; kx < 3; ++kx)
                aB[py * 3 + px] += w9[ky * 3 + kx] * xp[(py + ky) * 5 + px + kx];
      }
    }
#pragma unroll
    for (int p = 0; p < 9; ++p) {
      a1pA[(ks * 256 + co) * 9 + p] = aA[p];  // stride 9: conflict-free
      if (hasB) a1pB[(ks * 256 + co) * 9 + p] = aB[p];
    }
    __syncthreads();

    // combine split-K + BN1 + ReLU (first 4 waves)
    if (t < 256) {
      const float sc1 = bnp[t], sh1 = bnp[256 + t];
#pragma unroll
      for (int p = 0; p < 9; ++p) {
        float vA = a1pA[t * 9 + p] + a1pA[(256 + t) * 9 + p] +
                   a1pA[(512 + t) * 9 + p] + a1pA[(768 + t) * 9 + p];
        f9A[t * 12 + p] = fmaxf(vA * sc1 + sh1, 0.f);
        if (hasB) {
          float vB = a1pB[t * 9 + p] + a1pB[(256 + t) * 9 + p] +
                     a1pB[(512 + t) * 9 + p] + a1pB[(768 + t) * 9 + p];
          f9B[t * 12 + p] = fmaxf(vB * sc1 + sh1, 0.f);
        }
      }
    }
    __syncthreads();

    // conv2 partial over this wave's 64 ci, both candidates per weight read
    float accA = 0.f, accB = 0.f;
    for (int ci = ci0; ci < ci0 + 64; ++ci) {
      const float* wr = w2n + (size_t)ci * 2304 + co;
      float w9[9];
#pragma unroll
      for (int k = 0; k < 9; ++k) w9[k] = wr[k * 256];
      {
        float f9[12];
        const float4* fr = (const float4*)(f9A + ci * 12);
#pragma unroll
        for (int q = 0; q < 3; ++q) {
          float4 v = fr[q];
          f9[q * 4 + 0] = v.x; f9[q * 4 + 1] = v.y;
          f9[q * 4 + 2] = v.z; f9[q * 4 + 3] = v.w;
        }
#pragma unroll
        for (int k = 0; k < 9; ++k) accA += w9[k] * f9[k];
      }
      if (hasB) {
        float f9[12];
        const float4* fr = (const float4*)(f9B + ci * 12);
#pragma unroll
        for (int q = 0; q < 3; ++q) {
          float4 v = fr[q];
          f9[q * 4 + 0] = v.x; f9[q * 4 + 1] = v.y;
          f9[q * 4 + 2] = v.z; f9[q * 4 + 3] = v.w;
        }
#pragma unroll
        for (int k = 0; k < 9; ++k) accB += w9[k] * f9[k];
      }
    }
    accA_p[ks * 256 + co] = accA;
    if (hasB) accB_p[ks * 256 + co] = accB;
    __syncthreads();

    if (t < 256) {
      const float sc2 = bnp[512 + t], sh2 = bnp[768 + t], wf = bnp[1024 + t];
      float a = accA_p[t] + accA_p[256 + t] + accA_p[512 + t] + accA_p[768 + t];
      float pA = fmaxf(a * sc2 + sh2, 0.f) * wf;
      float pB = 0.f;
      if (hasB) {
        float bb = accB_p[t] + accB_p[256 + t] + accB_p[512 + t] + accB_p[768 + t];
        pB = fmaxf(bb * sc2 + sh2, 0.f) * wf;
      }
      for (int off = 32; off; off >>= 1) {
        pA += __shfl_xor(pA, off);
        pB += __shfl_xor(pB, off);
      }
      if ((t & 63) == 0) {
        redA[t >> 6] = pA;
        redB[t >> 6] = pB;
      }
    }
    __syncthreads();
    if (t == 0) {
      exlog[b * CCAP + c0] = redA[0] + redA[1] + redA[2] + redA[3] + b2[0];
      if (hasB)
        exlog[b * CCAP + c1] = redB[0] + redB[1] + redB[2] + redB[3] + b2[0];
    }
  }
}

// --- rank-sort exact logits, keep top-100 (jax tie-break: lower idx) --------
__global__ __launch_bounds__(CCAP) void final_topk(const float* __restrict__ exlog,
                                                   const int* __restrict__ cand,
                                                   const int* __restrict__ cnt,
                                                   int* __restrict__ tidx,
                                                   float* __restrict__ tlog) {
  const int b = blockIdx.x, t = threadIdx.x;
  __shared__ float v[CCAP];
  __shared__ int si[CCAP];
  const int n = cnt[b];
  float mv = (t < n) ? exlog[b * CCAP + t] : -3.0e38f;
  int s = (t < n) ? cand[b * CCAP + t] : 0x7FFFFFFF;
  v[t] = mv;
  si[t] = s;
  __syncthreads();
  int rank = 0;
  for (int j = 0; j < CCAP; ++j) {
    float vj = v[j];
    int sj = si[j];
    if (vj > mv || (vj == mv && sj < s)) ++rank;
  }
  if (t < n && rank < 100) {
    tidx[b * 100 + rank] = s;
    tlog[b * 100 + rank] = mv;
  }
}

// --- fused FFN + LN + heads + anchor (fp32 out), one block per query --------
__global__ __launch_bounds__(256) void head_kern(
    const short* __restrict__ featb, const int* __restrict__ tidx,
    const float* __restrict__ tlog, const float* __restrict__ tmpl,
    const float* __restrict__ w1, const float* __restrict__ b1,
    const float* __restrict__ lng, const float* __restrict__ lnb,
    const float* __restrict__ w2, const float* __restrict__ b2,
    const float* __restrict__ zw, const float* __restrict__ zb,
    const float* __restrict__ dmw, const float* __restrict__ dmb,
    const float* __restrict__ yw, const float* __restrict__ yb,
    const float* __restrict__ vw, const float* __restrict__ vb,
    float* __restrict__ out) {
  const int blk = blockIdx.x;  // 400
  const int b = blk / 100, q = blk % 100;
  const int t = threadIdx.x;
  const int lane = t & 63, wid = t >> 6;
  __shared__ float g[256];
  __shared__ float sx[256];
  __shared__ float red[4];
  __shared__ float heads[8];

  const int s = tidx[b * 100 + q];
  const float score = 1.f / (1.f + expf(-tlog[b * 100 + q]));
  const int ys = s >> 7, xs = s & 127;

  g[t] = bf2f(featb[(((size_t)(b * 128 + ys)) * WPITCH + xs + 1) * 256 + t]);
  __syncthreads();

  float x = b1[t];
  {
    const float* wr = w1 + (size_t)t * 256;
    for (int i = 0; i < 256; i += 4) {
      float4 wv = *(const float4*)(wr + i);
      x += g[i] * wv.x + g[i + 1] * wv.y + g[i + 2] * wv.z + g[i + 3] * wv.w;
    }
  }
  float sum = x;
  for (int off = 32; off; off >>= 1) sum += __shfl_xor(sum, off);
  if (lane == 0) red[wid] = sum;
  __syncthreads();
  float mu = (red[0] + red[1] + red[2] + red[3]) * (1.f / 256.f);
  __syncthreads();
  float d = x - mu;
  float q2 = d * d;
  for (int off = 32; off; off >>= 1) q2 += __shfl_xor(q2, off);
  if (lane == 0) red[wid] = q2;
  __syncthreads();
  float var = (red[0] + red[1] + red[2] + red[3]) * (1.f / 256.f);
  float xn = d * (1.f / sqrtf(var + 1e-5f)) * lng[t] + lnb[t];
  xn = fmaxf(xn, 0.f);
  sx[t] = xn;
  __syncthreads();
  float pf = b2[t];
  {
    const float* wr = w2 + (size_t)t * 256;
    for (int i = 0; i < 256; i += 4) {
      float4 wv = *(const float4*)(wr + i);
      pf += sx[i] * wv.x + sx[i + 1] * wv.y + sx[i + 2] * wv.z + sx[i + 3] * wv.w;
    }
  }
  pf *= (1.f + score);
  out[(size_t)(b * 100 + q) * 256 + t] = pf;

  const int k = t >> 5, l = t & 31;
  const float* hw;
  float hb;
  if (k == 0)      { hw = zw;                 hb = zb[0]; }
  else if (k < 4)  { hw = dmw + (k - 1) * 256; hb = dmb[k - 1]; }
  else if (k < 6)  { hw = yw + (k - 4) * 256;  hb = yb[k - 4]; }
  else             { hw = vw + (k - 6) * 256;  hb = vb[k - 6]; }
  float hp = 0.f;
#pragma unroll
  for (int r = 0; r < 8; ++r) {
    int i = l + r * 32;
    hp += g[i] * hw[i];
  }
  for (int off = 16; off; off >>= 1) hp += __shfl_xor(hp, off);
  if (l == 0) heads[k] = hp + hb;
  __syncthreads();

  if (t == 0) {
    const float* pa = tmpl + ((size_t)b * 900 + q) * 11;
    float p[11];
#pragma unroll
    for (int i = 0; i < 11; ++i) p[i] = pa[i];
    float a[11];
    a[0] = ((float)xs + 0.5f) * 0.8f - 51.2f;
    a[1] = ((float)ys + 0.5f) * 0.8f - 51.2f;
    a[2] = p[2] + 0.5f * heads[0];
#pragma unroll
    for (int i = 0; i < 3; ++i)
      a[3 + i] = p[3 + i] + 0.2f * fminf(fmaxf(heads[1 + i], -1.f), 1.f);
    float t0 = tanhf(heads[4]), t1 = tanhf(heads[5]);
    float nrm = fmaxf(sqrtf(t0 * t0 + t1 * t1), 1e-6f);
    a[6] = 0.7f * p[6] + 0.3f * t0 / nrm;
    a[7] = 0.7f * p[7] + 0.3f * t1 / nrm;
    a[8] = p[8] + 0.2f * fminf(fmaxf(heads[6], -2.f), 2.f);
    a[9] = p[9] + 0.2f * fminf(fmaxf(heads[7], -2.f), 2.f);
    a[10] = p[10];
    float* oa = out + 102400 + (size_t)(b * 100 + q) * 11;
#pragma unroll
    for (int i = 0; i < 11; ++i) oa[i] = a[i];
    out[106800 + b * 100 + q] = score;
  }
}

extern "C" void kernel_launch(void* const* d_in, const int* in_sizes, int n_in,
                              void* d_out, int out_size, void* d_ws, size_t ws_size,
                              hipStream_t stream) {
  (void)in_sizes; (void)n_in; (void)out_size; (void)ws_size;
  char* ws = (char*)d_ws;
  short* xn     = (short*)(ws + WSO_XN);
  short* featb  = (short*)(ws + WSO_FEATB);
  short* wp1    = (short*)(ws + WSO_WP1);
  short* wp2    = (short*)(ws + WSO_WP2);
  float* bnp    = (float*)(ws + WSO_BNP);
  float* logits = (float*)(ws + WSO_LOG);
  int*   cand   = (int*)(ws + WSO_CAND);
  int*   cnt    = (int*)(ws + WSO_CNT);
  float* exl    = (float*)(ws + WSO_EXL);
  int*   tidx   = (int*)(ws + WSO_TIDX);
  float* tlog   = (float*)(ws + WSO_TLOG);
  float* w1n    = (float*)(ws + WSO_W1N);
  float* w2n    = (float*)(ws + WSO_W2N);
  float* pbuf   = (float*)(ws + WSO_PBUF);  // aliases xn (dead after conv2)

  const float* bev = (const float*)d_in[0];

  wprep<<<2304, 256, 0, stream>>>((const float*)d_in[2], wp1, w1n);
  wprep<<<2304, 256, 0, stream>>>((const float*)d_in[7], wp2, w2n);
  bnprep<<<1, 256, 0, stream>>>(
      (const float*)d_in[3], (const float*)d_in[4], (const float*)d_in[5],
      (const float*)d_in[6], (const float*)d_in[8], (const float*)d_in[9],
      (const float*)d_in[10], (const float*)d_in[11], (const float*)d_in[12], bnp);
  padzero<<<1024, 256, 0, stream>>>(xn, featb);
  loginit<<<256, 256, 0, stream>>>(logits, (const float*)d_in[13]);
  nchw2nhwc<<<dim3(256, 4, 4), 256, 0, stream>>>(bev, xn);
  conv3x3<0><<<dim3(512, 2), 256, 0, stream>>>(xn, wp1, bnp, bnp + 256,
                                               nullptr, featb, nullptr);
  conv3x3<1><<<dim3(512, 2), 256, 0, stream>>>(featb, wp2, bnp + 512, bnp + 768,
                                               bnp + 1024, nullptr, logits);
  topk_radix<<<4, 1024, 0, stream>>>(logits, cand, cnt);
  // xn is dead from here on; pbuf reuses its storage.
  patchstage<<<dim3(CCAP, 4), 256, 0, stream>>>(bev, cand, cnt, pbuf);
  rescore<<<dim3(64, 4), 1024, 0, stream>>>(pbuf, w1n, w2n, bnp,
                                            (const float*)d_in[13], cand, cnt,
                                            exl);
  final_topk<<<4, CCAP, 0, stream>>>(exl, cand, cnt, tidx, tlog);
  head_kern<<<400, 256, 0, stream>>>(
      featb, tidx, tlog, (const float*)d_in[1],
      (const float*)d_in[14], (const float*)d_in[15], (const float*)d_in[16],
      (const float*)d_in[17], (const float*)d_in[18], (const float*)d_in[19],
      (const float*)d_in[20], (const float*)d_in[21], (const float*)d_in[22],
      (const float*)d_in[23], (const float*)d_in[24], (const float*)d_in[25],
      (const float*)d_in[26], (const float*)d_in[27], (float*)d_out);
}

// Round 9
// 540.002 us; speedup vs baseline: 1.3562x; 1.0112x over previous
//
#include <hip/hip_runtime.h>
#include <math.h>

// ---------------------------------------------------------------------------
// LiDARPriorQueryGenerator — MI355X (gfx950). FP32 I/O per reference dtypes.
// wprep2(both weights: bf16 [tap][co][ci] + fp32 [ci][tap][co]) -> smallprep
// (bn-fold, pad-zero, logit-init) -> NHWC bf16 (W padded 130) -> conv1 MFMA
// (single 130-row A tile, dw via ds_read offset) -> featb bf16 -> conv2 MFMA
// + fused 1x1 score -> RADIX-SELECT top>=128 -> patchstage -> EXACT fp32
// rescore (G=2 pairs, 1024 thr, 4-way split-K, scalar patches) -> final
// top-100 -> fused FFN/LN/heads/anchor.
// ---------------------------------------------------------------------------

typedef __attribute__((ext_vector_type(8))) short bf16x8;
typedef __attribute__((ext_vector_type(4))) float f32x4;

#define HW 16384
#define WPITCH 130   // padded width: col 0 and 129 are zero pads
#define CCAP 192     // candidate cap (count(key>=K*) typically 128..~132)
#define PSTR 28      // patch buffer stride (floats) per (cand, ci)
// workspace byte offsets
#define WSO_XN    0ULL           // bf16 NHWC padded input; LATER pbuf alias
#define WSO_FEATB 34078720ULL    // bf16 NHWC padded feat   (34,078,720)
#define WSO_WP1   68157440ULL    // bf16 [9][256][256] shared_w
#define WSO_WP2   69337088ULL    // bf16 [9][256][256] obj_w1
#define WSO_BNP   70516736ULL    // fp32 scale1,shift1,scale2,shift2,w2f (1280)
#define WSO_LOG   70521856ULL    // fp32 65536 logits
#define WSO_CAND  70784000ULL    // int 4*CCAP
#define WSO_CNT   70787072ULL    // int 4 (+pad)
#define WSO_EXL   70787136ULL    // fp32 4*CCAP
#define WSO_TIDX  70790208ULL    // int 4*100
#define WSO_TLOG  70791808ULL    // fp32 4*100
#define WSO_W1N   70793408ULL    // fp32 [ci][tap][co] shared_w (2,359,296)
#define WSO_W2N   73152704ULL    // fp32 [ci][tap][co] obj_w1   (2,359,296)
#define WSO_PBUF  WSO_XN         // fp32 [b][cand][ci][PSTR] patches (22 MB)

__device__ __forceinline__ float bf2f(short s) {
  return __uint_as_float(((unsigned)(unsigned short)s) << 16);
}
__device__ __forceinline__ short f2bf(float f) {  // RNE
  unsigned u = __float_as_uint(f);
  u += 0x7fffu + ((u >> 16) & 1u);
  return (short)(u >> 16);
}
__device__ __forceinline__ void gll16(const void* g, void* l) {
  __builtin_amdgcn_global_load_lds(
      (const __attribute__((address_space(1))) void*)g,
      (__attribute__((address_space(3))) void*)l, 16, 0, 0);
}

// --- prep: BOTH conv weights in one launch; coalesced read, two writes:
//   wp  bf16 [tap][co][ci]  (MFMA conv)     wn fp32 [ci][tap][co] (rescore)
__global__ void wprep2(const float* __restrict__ s1, const float* __restrict__ s2,
                       short* __restrict__ wp1, short* __restrict__ wp2,
                       float* __restrict__ wn1, float* __restrict__ wn2) {
  int bx = blockIdx.x;  // grid 4608
  const float* src;
  short* wp;
  float* wn;
  if (bx >= 2304) {
    src = s2; wp = wp2; wn = wn2; bx -= 2304;
  } else {
    src = s1; wp = wp1; wn = wn1;
  }
  int i = bx * 256 + threadIdx.x;
  float v = src[i];
  int k = i % 9;
  int r = i / 9;
  int ci = r & 255;
  int co = r >> 8;
  wp[(k * 256 + co) * 256 + ci] = f2bf(v);
  wn[(ci * 9 + k) * 256 + co] = v;
}

// --- prep: padzero (blocks 0..1023) + loginit (1024..1279) + bnfold (1280) --
__global__ void smallprep(const float* g1, const float* b1, const float* m1,
                          const float* v1, const float* g2, const float* b2,
                          const float* m2, const float* v2, const float* w2,
                          const float* ob2, float* __restrict__ bnp,
                          short* __restrict__ xn, short* __restrict__ featb,
                          float* __restrict__ logits) {
  const int blk = blockIdx.x, t = threadIdx.x;
  if (blk < 1024) {
    int i = blk * 256 + t;
    int c = i & 255;
    int r = i >> 8;
    int nh = r >> 1;
    int side = r & 1;
    size_t off = ((size_t)nh * WPITCH + (side ? 129 : 0)) * 256 + c;
    xn[off] = 0;
    featb[off] = 0;
  } else if (blk < 1280) {
    logits[(blk - 1024) * 256 + t] = ob2[0];
  } else {
    float s1 = g1[t] / sqrtf(v1[t] + 1e-5f);
    bnp[t] = s1;
    bnp[256 + t] = b1[t] - m1[t] * s1;
    float s2 = g2[t] / sqrtf(v2[t] + 1e-5f);
    bnp[512 + t] = s2;
    bnp[768 + t] = b2[t] - m2[t] * s2;
    bnp[1024 + t] = w2[t];
  }
}

// --- NCHW f32 -> NHWC bf16 (padded W) ---------------------------------------
__global__ __launch_bounds__(256) void nchw2nhwc(const float* __restrict__ in,
                                                 short* __restrict__ out) {
  __shared__ short tl[64 * 66];
  int n = blockIdx.z, c0 = blockIdx.y * 64, s0 = blockIdx.x * 64;
  int sl = threadIdx.x & 63, cl = threadIdx.x >> 6;
  for (int p = 0; p < 16; ++p) {
    int c = cl + p * 4;
    tl[c * 66 + sl] = f2bf(in[(((size_t)(n * 256 + c0 + c)) << 14) + s0 + sl]);
  }
  __syncthreads();
  int co = threadIdx.x & 63, so = threadIdx.x >> 6;
  for (int p = 0; p < 16; ++p) {
    int S = s0 + so + p * 4;
    int h = S >> 7, w = S & 127;
    out[(((size_t)(n * 128 + h)) * WPITCH + w + 1) * 256 + c0 + co] =
        tl[co * 66 + (so + p * 4)];
  }
}

// --- 3x3 conv + BN + ReLU via MFMA. Single 130-row A tile per (dh,c0)
// window; the dw shift is a ds_read row offset (A staged ONCE, not 3x).
// B: 3 tap tiles. One barrier drain covers 8 gll16 + tail -> 48 MFMA.
template <int OUT_LOGITS>
__global__ __launch_bounds__(256) void conv3x3(const short* __restrict__ inp,
                                               const short* __restrict__ wp,
                                               const float* __restrict__ scale,
                                               const float* __restrict__ shift,
                                               const float* __restrict__ w2f,
                                               short* __restrict__ outb,
                                               float* __restrict__ logits) {
  __shared__ short a_sm[132 * 32];     // rows 0..129 used (130-row tile)
  __shared__ short b_sm[3][128 * 32];
  const int t = threadIdx.x;
  const int wv = t >> 6, lane = t & 63;
  const int l15 = lane & 15, quad = lane >> 4;
  const int tile = blockIdx.x;
  const int img = tile >> 7;
  const int h = tile & 127;
  const int nblk = blockIdx.y;
  const int m0 = (wv & 1) << 6;
  const int n0 = (wv >> 1) << 6;

  f32x4 acc[4][4];
#pragma unroll
  for (int i = 0; i < 4; ++i)
#pragma unroll
    for (int j = 0; j < 4; ++j) {
      acc[i][j][0] = 0.f; acc[i][j][1] = 0.f;
      acc[i][j][2] = 0.f; acc[i][j][3] = 0.f;
    }

  for (int dhi = 0; dhi < 3; ++dhi) {
    const int hy = h + dhi - 1;
    if (hy < 0 || hy > 127) continue;  // block-uniform row-pad skip
    const size_t arow = ((size_t)(img * 128 + hy)) * WPITCH;
    const short* wbase = wp + ((size_t)(dhi * 3 * 256 + nblk * 128)) * 256;

    for (int c0 = 0; c0 < 256; c0 += 32) {
      __syncthreads();
      // stage A: positions [0,128) via 2 gll16 rounds (full-exec)
#pragma unroll
      for (int j = 0; j < 2; ++j) {
        const int seg = (j << 6) + (t >> 2);
        const int cc = t & 3;
        gll16(inp + (arow + seg) * 256 + c0 + cc * 8,
              a_sm + ((size_t)((j << 8) + t)) * 8);
      }
      // positions 128,129: plain dword load + LDS store (exec-mask-safe)
      if (t < 32) {
        const int r = t >> 4, dw = t & 15;
        const int* gsrc = (const int*)(inp + (arow + 128 + r) * 256 + c0) + dw;
        ((int*)a_sm)[(128 + r) * 16 + dw] = *gsrc;
      }
      // stage B: 3 taps of this dh row
#pragma unroll
      for (int dwi = 0; dwi < 3; ++dwi) {
        const short* wtap = wbase + (size_t)dwi * 65536;
#pragma unroll
        for (int j = 0; j < 2; ++j) {
          const int nrow = (j << 6) + (t >> 2);
          const int cc = t & 3;
          gll16(wtap + (size_t)nrow * 256 + c0 + cc * 8,
                b_sm[dwi] + ((size_t)((j << 8) + t)) * 8);
        }
      }
      __syncthreads();  // single drain -> 48 MFMA

#pragma unroll
      for (int dwi = 0; dwi < 3; ++dwi) {
        bf16x8 af[4], bfr[4];
#pragma unroll
        for (int i = 0; i < 4; ++i)
          af[i] = *(const bf16x8*)(a_sm + (dwi + m0 + i * 16 + l15) * 32 + quad * 8);
#pragma unroll
        for (int i = 0; i < 4; ++i)
          bfr[i] = *(const bf16x8*)(b_sm[dwi] + (n0 + i * 16 + l15) * 32 + quad * 8);
#pragma unroll
        for (int i = 0; i < 4; ++i)
#pragma unroll
          for (int j = 0; j < 4; ++j)
            acc[i][j] = __builtin_amdgcn_mfma_f32_16x16x32_bf16(af[i], bfr[j],
                                                                acc[i][j], 0, 0, 0);
      }
    }
  }

  // C/D map: col = lane&15, row = quad*4 + reg
  float sc[4], sh[4], wf[4];
#pragma unroll
  for (int j = 0; j < 4; ++j) {
    const int co = nblk * 128 + n0 + j * 16 + l15;
    sc[j] = scale[co];
    sh[j] = shift[co];
    if (OUT_LOGITS) wf[j] = w2f[co];
  }
  if (OUT_LOGITS) {
    float* lrow = logits + ((size_t)img << 14) + (h << 7);
#pragma unroll
    for (int i = 0; i < 4; ++i) {
#pragma unroll
      for (int r = 0; r < 4; ++r) {
        float part = 0.f;
#pragma unroll
        for (int j = 0; j < 4; ++j) {
          float v = fmaxf(acc[i][j][r] * sc[j] + sh[j], 0.f);
          part += v * wf[j];
        }
        part += __shfl_xor(part, 1);
        part += __shfl_xor(part, 2);
        part += __shfl_xor(part, 4);
        part += __shfl_xor(part, 8);
        if (l15 == 0)
          atomicAdd(&lrow[m0 + i * 16 + quad * 4 + r], part);
      }
    }
  } else {
    const size_t obase = ((size_t)(img * 128 + h)) * WPITCH + 1;
#pragma unroll
    for (int i = 0; i < 4; ++i) {
#pragma unroll
      for (int j = 0; j < 4; ++j) {
        const int co = nblk * 128 + n0 + j * 16 + l15;
#pragma unroll
        for (int r = 0; r < 4; ++r) {
          const int m = m0 + i * 16 + quad * 4 + r;
          float v = fmaxf(acc[i][j][r] * sc[j] + sh[j], 0.f);
          outb[(obase + m) * 256 + co] = f2bf(v);
        }
      }
    }
  }
}

// --- radix-select: all elements with key >= K* (exact rank-128 key) ---------
__global__ __launch_bounds__(1024) void topk_radix(const float* __restrict__ logits,
                                                   int* __restrict__ cand,
                                                   int* __restrict__ cnt_out) {
  __shared__ int hist[2048];
  __shared__ int wsum[16];
  __shared__ unsigned sel_bin;
  __shared__ int sel_above;
  __shared__ int cntr;
  const int b = blockIdx.x, t = threadIdx.x;
  const int lane = t & 63, wid = t >> 6;
  const float* L = logits + (size_t)b * HW;
  const int base = t * 16;
  unsigned kv[16];
#pragma unroll
  for (int i = 0; i < 4; ++i) {
    float4 v = *(const float4*)(L + base + i * 4);
    float f4[4] = {v.x, v.y, v.z, v.w};
#pragma unroll
    for (int j = 0; j < 4; ++j) {
      unsigned u = __float_as_uint(f4[j]);
      kv[i * 4 + j] = u ^ (((unsigned)((int)u >> 31)) | 0x80000000u);
    }
  }
  unsigned prefix = 0, pmask = 0;
  int need = 128;
  const int shifts[3] = {21, 10, 0};
  const int nbs[3] = {2048, 2048, 1024};

  for (int lev = 0; lev < 3; ++lev) {
    const int shift = shifts[lev];
    const int nb = nbs[lev];
    hist[t] = 0;
    hist[t + 1024] = 0;
    __syncthreads();
#pragma unroll
    for (int i = 0; i < 16; ++i)
      if ((kv[i] & pmask) == prefix)
        atomicAdd(&hist[(kv[i] >> shift) & (nb - 1)], 1);
    __syncthreads();
    const int cs = nb >> 10;
    const int bin_hi = nb - 1 - t * cs;
    const int c_hi = hist[bin_hi];
    const int c_lo = (cs == 2) ? hist[bin_hi - 1] : 0;
    const int s = c_hi + c_lo;
    int inc = s;
    for (int off = 1; off < 64; off <<= 1) {
      int nbr = __shfl_up(inc, off);
      if (lane >= off) inc += nbr;
    }
    if (lane == 63) wsum[wid] = inc;
    __syncthreads();
    if (wid == 0) {
      int wv = (lane < 16) ? wsum[lane] : 0;
      for (int off = 1; off < 16; off <<= 1) {
        int nbr = __shfl_up(wv, off);
        if (lane >= off) wv += nbr;
      }
      if (lane < 16) wsum[lane] = wv;
    }
    __syncthreads();
    const int excl = inc - s + (wid ? wsum[wid - 1] : 0);
    if (excl < need && need <= excl + s) {
      if (need <= excl + c_hi) {
        sel_bin = (unsigned)bin_hi;
        sel_above = excl;
      } else {
        sel_bin = (unsigned)(bin_hi - 1);
        sel_above = excl + c_hi;
      }
    }
    __syncthreads();
    prefix |= sel_bin << shift;
    pmask |= ((unsigned)(nb - 1)) << shift;
    need -= sel_above;
    __syncthreads();
  }
  if (t == 0) cntr = 0;
  __syncthreads();
#pragma unroll
  for (int i = 0; i < 16; ++i) {
    if (kv[i] >= prefix) {
      int p = atomicAdd(&cntr, 1);
      if (p < CCAP) cand[b * CCAP + p] = base + i;
    }
  }
  __syncthreads();
  if (t == 0) cnt_out[b] = (cntr < CCAP) ? cntr : CCAP;
}

// --- stage zero-padded 5x5x256 patches to global ----------------------------
__global__ __launch_bounds__(256) void patchstage(const float* __restrict__ x,
                                                  const int* __restrict__ cand,
                                                  const int* __restrict__ cnt,
                                                  float* __restrict__ pbuf) {
  const int c = blockIdx.x, b = blockIdx.y, t = threadIdx.x;
  if (c >= cnt[b]) return;
  const int s = cand[b * CCAP + c];
  const int h0 = (s >> 7) - 2, w0 = (s & 127) - 2;
  const float* xb = x + ((size_t)b << 22);
  float* pc = pbuf + (size_t)(b * CCAP + c) * (256 * PSTR);
#pragma unroll
  for (int k = 0; k < 25; ++k) {
    int e = t + (k << 8);
    int ci = e / 25;
    int rj = e - ci * 25;
    int r = rj / 5;
    int j = rj - r * 5;
    int hy = h0 + r, wx = w0 + j;
    float v = 0.f;
    if (hy >= 0 && hy < 128 && wx >= 0 && wx < 128)
      v = xb[((size_t)ci << 14) + (hy << 7) + wx];
    pc[ci * PSTR + rj] = v;
  }
}

// --- EXACT fp32 rescore: G=2 candidate pairs, 1024 thr, 4-way split-K -------
__global__ __launch_bounds__(1024) void rescore(const float* __restrict__ pbuf,
                                                const float* __restrict__ w1n,
                                                const float* __restrict__ w2n,
                                                const float* __restrict__ bnp,
                                                const float* __restrict__ b2,
                                                const int* __restrict__ cand,
                                                const int* __restrict__ cnt,
                                                float* __restrict__ exlog) {
  const int bx = blockIdx.x, b = blockIdx.y, t = threadIdx.x;
  const int n = cnt[b];
  const int co = t & 255;
  const int ks = __builtin_amdgcn_readfirstlane(t >> 8);  // wave-uniform
  const int ci0 = ks << 6;
  __shared__ float a1pA[4 * 256 * 9];
  __shared__ float a1pB[4 * 256 * 9];
  __shared__ float f9A[256 * 12];
  __shared__ float f9B[256 * 12];
  __shared__ float accA_p[4 * 256];
  __shared__ float accB_p[4 * 256];
  __shared__ float redA[4], redB[4];

  for (int pass = 0; pass < 2; ++pass) {
    const int c0 = bx + (pass ? 128 : 0);
    if (c0 >= n) break;  // block-uniform (pass 0 never breaks: n >= 128)
    const int c1 = bx + 64;
    const bool hasB = (pass == 0);
    if (pass) __syncthreads();

    const float* ppA = pbuf + ((size_t)(b * CCAP + c0)) * (256 * PSTR);
    const float* ppB = pbuf + ((size_t)(b * CCAP + (hasB ? c1 : c0))) * (256 * PSTR);

    float aA[9], aB[9];
#pragma unroll
    for (int p = 0; p < 9; ++p) { aA[p] = 0.f; aB[p] = 0.f; }
    for (int ci = ci0; ci < ci0 + 64; ++ci) {
      const float* wr = w1n + (size_t)ci * 2304 + co;
      float w9[9];
#pragma unroll
      for (int k = 0; k < 9; ++k) w9[k] = wr[k * 256];
      {
        const float* pc = ppA + ci * PSTR;
        float xp[25];
#pragma unroll
        for (int p = 0; p < 25; ++p) xp[p] = pc[p];
#pragma unroll
        for (int py = 0; py < 3; ++py)
#pragma unroll
          for (int px = 0; px < 3; ++px)
#pragma unroll
            for (int ky = 0; ky < 3; ++ky)
#pragma unroll
              for (int kx = 0; kx < 3; ++kx)
                aA[py * 3 + px] += w9[ky * 3 + kx] * xp[(py + ky) * 5 + px + kx];
      }
      if (hasB) {
        const float* pc = ppB + ci * PSTR;
        float xp[25];
#pragma unroll
        for (int p = 0; p < 25; ++p) xp[p] = pc[p];
#pragma unroll
        for (int py = 0; py < 3; ++py)
#pragma unroll
          for (int px = 0; px < 3; ++px)
#pragma unroll
            for (int ky = 0; ky < 3; ++ky)
#pragma unroll
              for (int kx = 0; kx < 3; ++kx)
                aB[py * 3 + px] += w9[ky * 3 + kx] * xp[(py + ky) * 5 + px + kx];
      }
    }
#pragma unroll
    for (int p = 0; p < 9; ++p) {
      a1pA[(ks * 256 + co) * 9 + p] = aA[p];
      if (hasB) a1pB[(ks * 256 + co) * 9 + p] = aB[p];
    }
    __syncthreads();

    if (t < 256) {
      const float sc1 = bnp[t], sh1 = bnp[256 + t];
#pragma unroll
      for (int p = 0; p < 9; ++p) {
        float vA = a1pA[t * 9 + p] + a1pA[(256 + t) * 9 + p] +
                   a1pA[(512 + t) * 9 + p] + a1pA[(768 + t) * 9 + p];
        f9A[t * 12 + p] = fmaxf(vA * sc1 + sh1, 0.f);
        if (hasB) {
          float vB = a1pB[t * 9 + p] + a1pB[(256 + t) * 9 + p] +
                     a1pB[(512 + t) * 9 + p] + a1pB[(768 + t) * 9 + p];
          f9B[t * 12 + p] = fmaxf(vB * sc1 + sh1, 0.f);
        }
      }
    }
    __syncthreads();

    float accA = 0.f, accB = 0.f;
    for (int ci = ci0; ci < ci0 + 64; ++ci) {
      const float* wr = w2n + (size_t)ci * 2304 + co;
      float w9[9];
#pragma unroll
      for (int k = 0; k < 9; ++k) w9[k] = wr[k * 256];
      {
        float f9[12];
        const float4* fr = (const float4*)(f9A + ci * 12);
#pragma unroll
        for (int q = 0; q < 3; ++q) {
          float4 v = fr[q];
          f9[q * 4 + 0] = v.x; f9[q * 4 + 1] = v.y;
          f9[q * 4 + 2] = v.z; f9[q * 4 + 3] = v.w;
        }
#pragma unroll
        for (int k = 0; k < 9; ++k) accA += w9[k] * f9[k];
      }
      if (hasB) {
        float f9[12];
        const float4* fr = (const float4*)(f9B + ci * 12);
#pragma unroll
        for (int q = 0; q < 3; ++q) {
          float4 v = fr[q];
          f9[q * 4 + 0] = v.x; f9[q * 4 + 1] = v.y;
          f9[q * 4 + 2] = v.z; f9[q * 4 + 3] = v.w;
        }
#pragma unroll
        for (int k = 0; k < 9; ++k) accB += w9[k] * f9[k];
      }
    }
    accA_p[ks * 256 + co] = accA;
    if (hasB) accB_p[ks * 256 + co] = accB;
    __syncthreads();

    if (t < 256) {
      const float sc2 = bnp[512 + t], sh2 = bnp[768 + t], wf = bnp[1024 + t];
      float a = accA_p[t] + accA_p[256 + t] + accA_p[512 + t] + accA_p[768 + t];
      float pA = fmaxf(a * sc2 + sh2, 0.f) * wf;
      float pB = 0.f;
      if (hasB) {
        float bb = accB_p[t] + accB_p[256 + t] + accB_p[512 + t] + accB_p[768 + t];
        pB = fmaxf(bb * sc2 + sh2, 0.f) * wf;
      }
      for (int off = 32; off; off >>= 1) {
        pA += __shfl_xor(pA, off);
        pB += __shfl_xor(pB, off);
      }
      if ((t & 63) == 0) {
        redA[t >> 6] = pA;
        redB[t >> 6] = pB;
      }
    }
    __syncthreads();
    if (t == 0) {
      exlog[b * CCAP + c0] = redA[0] + redA[1] + redA[2] + redA[3] + b2[0];
      if (hasB)
        exlog[b * CCAP + c1] = redB[0] + redB[1] + redB[2] + redB[3] + b2[0];
    }
  }
}

// --- rank-sort exact logits, keep top-100 (jax tie-break: lower idx) --------
__global__ __launch_bounds__(CCAP) void final_topk(const float* __restrict__ exlog,
                                                   const int* __restrict__ cand,
                                                   const int* __restrict__ cnt,
                                                   int* __restrict__ tidx,
                                                   float* __restrict__ tlog) {
  const int b = blockIdx.x, t = threadIdx.x;
  __shared__ float v[CCAP];
  __shared__ int si[CCAP];
  const int n = cnt[b];
  float mv = (t < n) ? exlog[b * CCAP + t] : -3.0e38f;
  int s = (t < n) ? cand[b * CCAP + t] : 0x7FFFFFFF;
  v[t] = mv;
  si[t] = s;
  __syncthreads();
  int rank = 0;
  for (int j = 0; j < CCAP; ++j) {
    float vj = v[j];
    int sj = si[j];
    if (vj > mv || (vj == mv && sj < s)) ++rank;
  }
  if (t < n && rank < 100) {
    tidx[b * 100 + rank] = s;
    tlog[b * 100 + rank] = mv;
  }
}

// --- fused FFN + LN + heads + anchor (fp32 out), one block per query --------
__global__ __launch_bounds__(256) void head_kern(
    const short* __restrict__ featb, const int* __restrict__ tidx,
    const float* __restrict__ tlog, const float* __restrict__ tmpl,
    const float* __restrict__ w1, const float* __restrict__ b1,
    const float* __restrict__ lng, const float* __restrict__ lnb,
    const float* __restrict__ w2, const float* __restrict__ b2,
    const float* __restrict__ zw, const float* __restrict__ zb,
    const float* __restrict__ dmw, const float* __restrict__ dmb,
    const float* __restrict__ yw, const float* __restrict__ yb,
    const float* __restrict__ vw, const float* __restrict__ vb,
    float* __restrict__ out) {
  const int blk = blockIdx.x;  // 400
  const int b = blk / 100, q = blk % 100;
  const int t = threadIdx.x;
  const int lane = t & 63, wid = t >> 6;
  __shared__ float g[256];
  __shared__ float sx[256];
  __shared__ float red[4];
  __shared__ float heads[8];

  const int s = tidx[b * 100 + q];
  const float score = 1.f / (1.f + expf(-tlog[b * 100 + q]));
  const int ys = s >> 7, xs = s & 127;

  g[t] = bf2f(featb[(((size_t)(b * 128 + ys)) * WPITCH + xs + 1) * 256 + t]);
  __syncthreads();

  float x = b1[t];
  {
    const float* wr = w1 + (size_t)t * 256;
    for (int i = 0; i < 256; i += 4) {
      float4 wv = *(const float4*)(wr + i);
      x += g[i] * wv.x + g[i + 1] * wv.y + g[i + 2] * wv.z + g[i + 3] * wv.w;
    }
  }
  float sum = x;
  for (int off = 32; off; off >>= 1) sum += __shfl_xor(sum, off);
  if (lane == 0) red[wid] = sum;
  __syncthreads();
  float mu = (red[0] + red[1] + red[2] + red[3]) * (1.f / 256.f);
  __syncthreads();
  float d = x - mu;
  float q2 = d * d;
  for (int off = 32; off; off >>= 1) q2 += __shfl_xor(q2, off);
  if (lane == 0) red[wid] = q2;
  __syncthreads();
  float var = (red[0] + red[1] + red[2] + red[3]) * (1.f / 256.f);
  float xn = d * (1.f / sqrtf(var + 1e-5f)) * lng[t] + lnb[t];
  xn = fmaxf(xn, 0.f);
  sx[t] = xn;
  __syncthreads();
  float pf = b2[t];
  {
    const float* wr = w2 + (size_t)t * 256;
    for (int i = 0; i < 256; i += 4) {
      float4 wv = *(const float4*)(wr + i);
      pf += sx[i] * wv.x + sx[i + 1] * wv.y + sx[i + 2] * wv.z + sx[i + 3] * wv.w;
    }
  }
  pf *= (1.f + score);
  out[(size_t)(b * 100 + q) * 256 + t] = pf;

  const int k = t >> 5, l = t & 31;
  const float* hw;
  float hb;
  if (k == 0)      { hw = zw;                 hb = zb[0]; }
  else if (k < 4)  { hw = dmw + (k - 1) * 256; hb = dmb[k - 1]; }
  else if (k < 6)  { hw = yw + (k - 4) * 256;  hb = yb[k - 4]; }
  else             { hw = vw + (k - 6) * 256;  hb = vb[k - 6]; }
  float hp = 0.f;
#pragma unroll
  for (int r = 0; r < 8; ++r) {
    int i = l + r * 32;
    hp += g[i] * hw[i];
  }
  for (int off = 16; off; off >>= 1) hp += __shfl_xor(hp, off);
  if (l == 0) heads[k] = hp + hb;
  __syncthreads();

  if (t == 0) {
    const float* pa = tmpl + ((size_t)b * 900 + q) * 11;
    float p[11];
#pragma unroll
    for (int i = 0; i < 11; ++i) p[i] = pa[i];
    float a[11];
    a[0] = ((float)xs + 0.5f) * 0.8f - 51.2f;
    a[1] = ((float)ys + 0.5f) * 0.8f - 51.2f;
    a[2] = p[2] + 0.5f * heads[0];
#pragma unroll
    for (int i = 0; i < 3; ++i)
      a[3 + i] = p[3 + i] + 0.2f * fminf(fmaxf(heads[1 + i], -1.f), 1.f);
    float t0 = tanhf(heads[4]), t1 = tanhf(heads[5]);
    float nrm = fmaxf(sqrtf(t0 * t0 + t1 * t1), 1e-6f);
    a[6] = 0.7f * p[6] + 0.3f * t0 / nrm;
    a[7] = 0.7f * p[7] + 0.3f * t1 / nrm;
    a[8] = p[8] + 0.2f * fminf(fmaxf(heads[6], -2.f), 2.f);
    a[9] = p[9] + 0.2f * fminf(fmaxf(heads[7], -2.f), 2.f);
    a[10] = p[10];
    float* oa = out + 102400 + (size_t)(b * 100 + q) * 11;
#pragma unroll
    for (int i = 0; i < 11; ++i) oa[i] = a[i];
    out[106800 + b * 100 + q] = score;
  }
}

extern "C" void kernel_launch(void* const* d_in, const int* in_sizes, int n_in,
                              void* d_out, int out_size, void* d_ws, size_t ws_size,
                              hipStream_t stream) {
  (void)in_sizes; (void)n_in; (void)out_size; (void)ws_size;
  char* ws = (char*)d_ws;
  short* xn     = (short*)(ws + WSO_XN);
  short* featb  = (short*)(ws + WSO_FEATB);
  short* wp1    = (short*)(ws + WSO_WP1);
  short* wp2    = (short*)(ws + WSO_WP2);
  float* bnp    = (float*)(ws + WSO_BNP);
  float* logits = (float*)(ws + WSO_LOG);
  int*   cand   = (int*)(ws + WSO_CAND);
  int*   cnt    = (int*)(ws + WSO_CNT);
  float* exl    = (float*)(ws + WSO_EXL);
  int*   tidx   = (int*)(ws + WSO_TIDX);
  float* tlog   = (float*)(ws + WSO_TLOG);
  float* w1n    = (float*)(ws + WSO_W1N);
  float* w2n    = (float*)(ws + WSO_W2N);
  float* pbuf   = (float*)(ws + WSO_PBUF);  // aliases xn (dead after conv2)

  const float* bev = (const float*)d_in[0];

  wprep2<<<4608, 256, 0, stream>>>((const float*)d_in[2], (const float*)d_in[7],
                                   wp1, wp2, w1n, w2n);
  smallprep<<<1281, 256, 0, stream>>>(
      (const float*)d_in[3], (const float*)d_in[4], (const float*)d_in[5],
      (const float*)d_in[6], (const float*)d_in[8], (const float*)d_in[9],
      (const float*)d_in[10], (const float*)d_in[11], (const float*)d_in[12],
      (const float*)d_in[13], bnp, xn, featb, logits);
  nchw2nhwc<<<dim3(256, 4, 4), 256, 0, stream>>>(bev, xn);
  conv3x3<0><<<dim3(512, 2), 256, 0, stream>>>(xn, wp1, bnp, bnp + 256,
                                               nullptr, featb, nullptr);
  conv3x3<1><<<dim3(512, 2), 256, 0, stream>>>(featb, wp2, bnp + 512, bnp + 768,
                                               bnp + 1024, nullptr, logits);
  topk_radix<<<4, 1024, 0, stream>>>(logits, cand, cnt);
  // xn is dead from here on; pbuf reuses its storage.
  patchstage<<<dim3(CCAP, 4), 256, 0, stream>>>(bev, cand, cnt, pbuf);
  rescore<<<dim3(64, 4), 1024, 0, stream>>>(pbuf, w1n, w2n, bnp,
                                            (const float*)d_in[13], cand, cnt,
                                            exl);
  final_topk<<<4, CCAP, 0, stream>>>(exl, cand, cnt, tidx, tlog);
  head_kern<<<400, 256, 0, stream>>>(
      featb, tidx, tlog, (const float*)d_in[1],
      (const float*)d_in[14], (const float*)d_in[15], (const float*)d_in[16],
      (const float*)d_in[17], (const float*)d_in[18], (const float*)d_in[19],
      (const float*)d_in[20], (const float*)d_in[21], (const float*)d_in[22],
      (const float*)d_in[23], (const float*)d_in[24], (const float*)d_in[25],
      (const float*)d_in[26], (const float*)d_in[27], (float*)d_out);
}